// Round 1
// baseline (1364.938 us; speedup 1.0000x reference)
//
#include <hip/hip_runtime.h>

#define TPB 256

// ---------- small kernels ----------

// dst[b*HW+p] = sum_c src[b,c,p]^2
__global__ void sq_sum_kernel(const float* __restrict__ src, float* __restrict__ dst,
                              int C, int HW) {
    int idx = blockIdx.x * TPB + threadIdx.x;
    int b = idx / HW, p = idx - b * HW;
    const float* s = src + (size_t)b * C * HW + p;
    float acc = 0.f;
    for (int c = 0; c < C; ++c) { float v = s[(size_t)c * HW]; acc += v * v; }
    dst[idx] = acc;
}

// pn[b,y,x] = sum over KxK window (zero pad) of s
template<int K, int PAD>
__global__ void win_sum_kernel(const float* __restrict__ s, float* __restrict__ pn,
                               int H, int W) {
    int idx = blockIdx.x * TPB + threadIdx.x;
    int b = idx / (H * W); int rem = idx - b * H * W;
    int y = rem / W, x = rem - y * W;
    const float* sb = s + (size_t)b * H * W;
    float acc = 0.f;
    #pragma unroll
    for (int ki = 0; ki < K; ++ki) {
        int yy = y - PAD + ki;
        if (yy < 0 || yy >= H) continue;
        #pragma unroll
        for (int kj = 0; kj < K; ++kj) {
            int xx = x - PAD + kj;
            if (xx < 0 || xx >= W) continue;
            acc += sb[yy * W + xx];
        }
    }
    pn[idx] = acc;
}

// wn[o] = sum_d w[o,d]^2 ; one 64-lane wave per o
__global__ void wn_kernel(const float* __restrict__ w, float* __restrict__ wn, int D) {
    int o = blockIdx.x;
    int lane = threadIdx.x;
    const float* row = w + (size_t)o * D;
    float acc = 0.f;
    for (int i = lane; i < D; i += 64) { float v = row[i]; acc += v * v; }
    #pragma unroll
    for (int off = 32; off >= 1; off >>= 1) acc += __shfl_down(acc, off);
    if (lane == 0) wn[o] = acc;
}

// ---------- fused RBF conv (+gauss+crelu, optional 2x2 sfm) ----------
// Block: 256 threads = 64 spatial (8x8, each owns 2x2 pre-pool pixels) x 4 o-groups.
// Each thread: 8 output channels x 2x2 pixels = 32 accumulators.
// LDS: input tile [CC][16+K-1][16+K] (pad +1), weights transposed [CC*K*K][32].
template<int K, int CC, bool DO_SFM>
__launch_bounds__(256)
__global__ void rbf_conv_kernel(const float* __restrict__ in, const float* __restrict__ w,
                                const float* __restrict__ pn, const float* __restrict__ wn,
                                const float* __restrict__ stdp, const float* __restrict__ biasp,
                                const float* __restrict__ alphap,
                                float* __restrict__ out,
                                int C, int O, int H, int otiles, int sptiles) {
    constexpr int PAD = K / 2;
    constexpr int IT = 16 + K - 1;
    constexpr int DL = CC * K * K;
    __shared__ float in_s[CC][IT][IT + 1];
    __shared__ float w_s[DL][32];

    int bid = blockIdx.x;
    int tx = bid % sptiles; bid /= sptiles;
    int ty = bid % sptiles; bid /= sptiles;
    int ot = bid % otiles;  int b = bid / otiles;
    int tid = threadIdx.x;
    int sp = tid & 63, og = tid >> 6;
    int sy = sp >> 3, sx = sp & 7;
    int o0 = ot * 32, y0 = ty * 16, x0 = tx * 16;
    const int W = H;
    const float* inb = in + (size_t)b * C * H * W;
    const int DTOT = C * K * K;

    float acc[8][2][2];
    #pragma unroll
    for (int r = 0; r < 8; ++r)
        acc[r][0][0] = acc[r][0][1] = acc[r][1][0] = acc[r][1][1] = 0.f;

    for (int c0 = 0; c0 < C; c0 += CC) {
        __syncthreads();
        for (int idx = tid; idx < CC * IT * IT; idx += 256) {
            int ch = idx / (IT * IT), rem = idx - ch * (IT * IT);
            int iy = rem / IT, ix = rem - iy * IT;
            int y = y0 - PAD + iy, x = x0 - PAD + ix;
            float v = 0.f;
            if (y >= 0 && y < H && x >= 0 && x < W)
                v = inb[(size_t)(c0 + ch) * H * W + y * W + x];
            in_s[ch][iy][ix] = v;
        }
        for (int idx = tid; idx < DL * 32; idx += 256) {
            int dl = idx >> 5, ol = idx & 31;
            w_s[dl][ol] = w[(size_t)(o0 + ol) * DTOT + c0 * K * K + dl];
        }
        __syncthreads();
        for (int c = 0; c < CC; ++c) {
            #pragma unroll
            for (int ki = 0; ki < K; ++ki) {
                #pragma unroll
                for (int kj = 0; kj < K; ++kj) {
                    int dl = c * K * K + ki * K + kj;
                    float i00 = in_s[c][2 * sy + ki][2 * sx + kj];
                    float i01 = in_s[c][2 * sy + ki][2 * sx + kj + 1];
                    float i10 = in_s[c][2 * sy + 1 + ki][2 * sx + kj];
                    float i11 = in_s[c][2 * sy + 1 + ki][2 * sx + kj + 1];
                    #pragma unroll
                    for (int r = 0; r < 8; ++r) {
                        float wv = w_s[dl][og * 8 + r];
                        acc[r][0][0] += wv * i00;
                        acc[r][0][1] += wv * i01;
                        acc[r][1][0] += wv * i10;
                        acc[r][1][1] += wv * i11;
                    }
                }
            }
        }
    }

    float stdv = stdp[0], bias = biasp[0];
    float inv2s2 = 1.f / (2.f * stdv * stdv);
    float p[2][2];
    #pragma unroll
    for (int dy = 0; dy < 2; ++dy)
        #pragma unroll
        for (int dx = 0; dx < 2; ++dx)
            p[dy][dx] = pn[(size_t)b * H * W + (size_t)(y0 + 2 * sy + dy) * W + (x0 + 2 * sx + dx)];

    if constexpr (DO_SFM) {
        float a0 = alphap[0], a1 = alphap[1], a2 = alphap[2], a3 = alphap[3];
        int Ho = H >> 1;
        #pragma unroll
        for (int r = 0; r < 8; ++r) {
            int o = o0 + og * 8 + r;
            float wno = wn[o];
            float sfm = 0.f;
            #pragma unroll
            for (int dy = 0; dy < 2; ++dy)
                #pragma unroll
                for (int dx = 0; dx < 2; ++dx) {
                    float d2 = fmaxf(p[dy][dx] + wno - 2.f * acc[r][dy][dx], 0.f);
                    float g = __expf(-d2 * inv2s2);
                    g = (g >= bias) ? g : 0.f;
                    float al = (dy == 0) ? (dx == 0 ? a0 : a1) : (dx == 0 ? a2 : a3);
                    sfm += al * g;
                }
            out[(((size_t)b * O + o) * Ho + (ty * 8 + sy)) * Ho + (tx * 8 + sx)] = 0.25f * sfm;
        }
    } else {
        #pragma unroll
        for (int r = 0; r < 8; ++r) {
            int o = o0 + og * 8 + r;
            float wno = wn[o];
            #pragma unroll
            for (int dy = 0; dy < 2; ++dy)
                #pragma unroll
                for (int dx = 0; dx < 2; ++dx) {
                    float d2 = fmaxf(p[dy][dx] + wno - 2.f * acc[r][dy][dx], 0.f);
                    float g = __expf(-d2 * inv2s2);
                    g = (g >= bias) ? g : 0.f;
                    out[(((size_t)b * O + o) * H + (y0 + 2 * sy + dy)) * W + (x0 + 2 * sx + dx)] = g;
                }
        }
    }
}

// ---------- FC: out[b,j] = sum_i h3[b,i]*fw[j,i] + fb[j] ----------
// Pass 1: block = (jt of 4 j's) x (chunk of 4096 i's); 64 partial sums per block.
__launch_bounds__(256)
__global__ void fc_partial_kernel(const float* __restrict__ h3, const float* __restrict__ fw,
                                  float* __restrict__ partial) {
    const int KI = 384 * 32 * 32;
    int bid = blockIdx.x;
    int jt = bid / 96, ch = bid - jt * 96;
    int tid = threadIdx.x;
    int j0 = jt * 4;
    float acc[4][16];
    #pragma unroll
    for (int jj = 0; jj < 4; ++jj)
        #pragma unroll
        for (int b = 0; b < 16; ++b) acc[jj][b] = 0.f;
    int ibase = ch * 4096 + tid;
    for (int ii = 0; ii < 16; ++ii) {
        int i = ibase + ii * 256;
        float hv[16];
        #pragma unroll
        for (int b = 0; b < 16; ++b) hv[b] = h3[(size_t)b * KI + i];
        #pragma unroll
        for (int jj = 0; jj < 4; ++jj) {
            float wv = fw[(size_t)(j0 + jj) * KI + i];
            #pragma unroll
            for (int b = 0; b < 16; ++b) acc[jj][b] += wv * hv[b];
        }
    }
    __shared__ float red[4][64];
    int lane = tid & 63, wv_ = tid >> 6;
    #pragma unroll
    for (int jj = 0; jj < 4; ++jj)
        #pragma unroll
        for (int b = 0; b < 16; ++b) {
            float v = acc[jj][b];
            v += __shfl_down(v, 32); v += __shfl_down(v, 16); v += __shfl_down(v, 8);
            v += __shfl_down(v, 4);  v += __shfl_down(v, 2);  v += __shfl_down(v, 1);
            if (lane == 0) red[wv_][jj * 16 + b] = v;
        }
    __syncthreads();
    if (tid < 64)
        partial[(size_t)bid * 64 + tid] = red[0][tid] + red[1][tid] + red[2][tid] + red[3][tid];
}

__global__ void fc_final_kernel(const float* __restrict__ partial, const float* __restrict__ fb,
                                float* __restrict__ outp) {
    int t = blockIdx.x * TPB + threadIdx.x;
    if (t >= 1600) return;
    int b = t / 100, j = t - b * 100;
    int jt = j >> 2, jj = j & 3;
    float s = fb[j];
    for (int ch = 0; ch < 96; ++ch)
        s += partial[(size_t)(jt * 96 + ch) * 64 + jj * 16 + b];
    outp[t] = s;
}

// ---------- launch ----------
extern "C" void kernel_launch(void* const* d_in, const int* in_sizes, int n_in,
                              void* d_out, int out_size, void* d_ws, size_t ws_size,
                              hipStream_t stream) {
    const float* x      = (const float*)d_in[0];
    const float* w1     = (const float*)d_in[1];
    const float* std1   = (const float*)d_in[2];
    const float* bias1  = (const float*)d_in[3];
    const float* alpha1 = (const float*)d_in[4];
    const float* w2     = (const float*)d_in[5];
    const float* std2   = (const float*)d_in[6];
    const float* bias2  = (const float*)d_in[7];
    const float* alpha2 = (const float*)d_in[8];
    const float* w3     = (const float*)d_in[9];
    const float* std3   = (const float*)d_in[10];
    const float* bias3  = (const float*)d_in[11];
    const float* fc_w   = (const float*)d_in[12];
    const float* fc_b   = (const float*)d_in[13];
    float* out = (float*)d_out;
    float* ws  = (float*)d_ws;

    // ws layout (floats); total ~16.5M floats ~= 66 MB
    float* pn1  = ws;                 // 16*128*128 = 262144
    float* h1   = pn1 + 262144;       // 16*96*64*64 = 6291456
    float* sbuf = h1 + 6291456;       // 262144 (reused for all sq-sums)
    float* pn2  = sbuf + 262144;      // 65536
    float* h2   = pn2 + 65536;        // 16*192*32*32 = 3145728
    float* pn3  = h2 + 3145728;       // 16384
    float* h3   = pn3 + 16384;        // 16*384*32*32 = 6291456
    float* wn1  = h3 + 6291456;       // 96
    float* wn2  = wn1 + 96;           // 192
    float* wn3  = wn2 + 192;          // 384
    float* fcp  = wn3 + 384;          // 2400*64 = 153600

    dim3 B(TPB);

    // block 1: x[16,3,128,128] -> h1[16,96,64,64]
    sq_sum_kernel<<<dim3(16 * 16384 / TPB), B, 0, stream>>>(x, sbuf, 3, 16384);
    win_sum_kernel<5, 2><<<dim3(16 * 16384 / TPB), B, 0, stream>>>(sbuf, pn1, 128, 128);
    wn_kernel<<<dim3(96), dim3(64), 0, stream>>>(w1, wn1, 75);
    rbf_conv_kernel<5, 3, true><<<dim3(16 * 3 * 8 * 8), B, 0, stream>>>(
        x, w1, pn1, wn1, std1, bias1, alpha1, h1, 3, 96, 128, 3, 8);

    // block 2: h1 -> h2[16,192,32,32]
    sq_sum_kernel<<<dim3(16 * 4096 / TPB), B, 0, stream>>>(h1, sbuf, 96, 4096);
    win_sum_kernel<5, 2><<<dim3(16 * 4096 / TPB), B, 0, stream>>>(sbuf, pn2, 64, 64);
    wn_kernel<<<dim3(192), dim3(64), 0, stream>>>(w2, wn2, 2400);
    rbf_conv_kernel<5, 8, true><<<dim3(16 * 6 * 4 * 4), B, 0, stream>>>(
        h1, w2, pn2, wn2, std2, bias2, alpha2, h2, 96, 192, 64, 6, 4);

    // block 3: h2 -> h3[16,384,32,32] (no sfm)
    sq_sum_kernel<<<dim3(16 * 1024 / TPB), B, 0, stream>>>(h2, sbuf, 192, 1024);
    win_sum_kernel<3, 1><<<dim3(16 * 1024 / TPB), B, 0, stream>>>(sbuf, pn3, 32, 32);
    wn_kernel<<<dim3(384), dim3(64), 0, stream>>>(w3, wn3, 1728);
    rbf_conv_kernel<3, 8, false><<<dim3(16 * 12 * 2 * 2), B, 0, stream>>>(
        h2, w3, pn3, wn3, std3, bias3, nullptr, h3, 192, 384, 32, 12, 2);

    // fc
    fc_partial_kernel<<<dim3(25 * 96), B, 0, stream>>>(h3, fc_w, fcp);
    fc_final_kernel<<<dim3((1600 + TPB - 1) / TPB), B, 0, stream>>>(fcp, fc_b, out);
}

// Round 2
// 356.968 us; speedup vs baseline: 3.8237x; 3.8237x over previous
//
#include <hip/hip_runtime.h>

#define TPB 256

typedef short bf16x8 __attribute__((ext_vector_type(8)));
typedef float f32x4 __attribute__((ext_vector_type(4)));

__device__ inline unsigned short f2bf(float f) {
    unsigned int u = __float_as_uint(f);
    unsigned int r = (u + 0x7fffu + ((u >> 16) & 1u)) >> 16;
    return (unsigned short)r;
}
__device__ inline float bf2f(unsigned short h) {
    return __uint_as_float(((unsigned int)h) << 16);
}

// ---------- small kernels ----------

// dst[b*HW+p] = sum_c src[b,c,p]^2  (fp32 channel-first input; used for x)
__global__ void sq_sum_kernel(const float* __restrict__ src, float* __restrict__ dst,
                              int C, int HW) {
    int idx = blockIdx.x * TPB + threadIdx.x;
    int b = idx / HW, p = idx - b * HW;
    const float* s = src + (size_t)b * C * HW + p;
    float acc = 0.f;
    for (int c = 0; c < C; ++c) { float v = s[(size_t)c * HW]; acc += v * v; }
    dst[idx] = acc;
}

// dst[idx] = sum_c src[idx*C+c]^2  (bf16 channel-last input)
template<int C>
__global__ void sq_cl_kernel(const unsigned short* __restrict__ src, float* __restrict__ dst) {
    int idx = blockIdx.x * TPB + threadIdx.x;
    const unsigned short* s = src + (size_t)idx * C;
    float acc = 0.f;
    #pragma unroll
    for (int c = 0; c < C; c += 8) {
        bf16x8 v = *(const bf16x8*)&s[c];
        #pragma unroll
        for (int j = 0; j < 8; ++j) { float f = bf2f((unsigned short)v[j]); acc += f * f; }
    }
    dst[idx] = acc;
}

// pn[b,y,x] = sum over KxK window (zero pad) of s
template<int K, int PAD>
__global__ void win_sum_kernel(const float* __restrict__ s, float* __restrict__ pn,
                               int H, int W) {
    int idx = blockIdx.x * TPB + threadIdx.x;
    int b = idx / (H * W); int rem = idx - b * H * W;
    int y = rem / W, x = rem - y * W;
    const float* sb = s + (size_t)b * H * W;
    float acc = 0.f;
    #pragma unroll
    for (int ki = 0; ki < K; ++ki) {
        int yy = y - PAD + ki;
        if (yy < 0 || yy >= H) continue;
        #pragma unroll
        for (int kj = 0; kj < K; ++kj) {
            int xx = x - PAD + kj;
            if (xx < 0 || xx >= W) continue;
            acc += sb[yy * W + xx];
        }
    }
    pn[idx] = acc;
}

// wn[o] = sum_d w[o,d]^2 ; one 64-lane wave per o
__global__ void wn_kernel(const float* __restrict__ w, float* __restrict__ wn, int D) {
    int o = blockIdx.x;
    int lane = threadIdx.x;
    const float* row = w + (size_t)o * D;
    float acc = 0.f;
    for (int i = lane; i < D; i += 64) { float v = row[i]; acc += v * v; }
    #pragma unroll
    for (int off = 32; off >= 1; off >>= 1) acc += __shfl_down(acc, off);
    if (lane == 0) wn[o] = acc;
}

// reorder weights [O][C*KK] (c-major) -> bf16 [O][KK*C] (tap-major)
__global__ void wt_reorder_kernel(const float* __restrict__ w, unsigned short* __restrict__ wbf,
                                  int O, int C, int KK) {
    int idx = blockIdx.x * TPB + threadIdx.x;
    if (idx >= O * C * KK) return;
    int c = idx % C; int t = idx / C; int tap = t % KK; int o = t / KK;
    wbf[idx] = f2bf(w[((size_t)o * C + c) * KK + tap]);
}

// ---------- conv1: fp32 direct (C=3), epilogue writes bf16 channel-last ----------
// Block: 256 thr = 64 spatial (8x8, each 2x2 pre-pool px) x 4 o-groups of 8.
__launch_bounds__(256)
__global__ void conv1_kernel(const float* __restrict__ in, const float* __restrict__ w,
                             const float* __restrict__ pn, const float* __restrict__ wn,
                             const float* __restrict__ stdp, const float* __restrict__ biasp,
                             const float* __restrict__ alphap,
                             unsigned short* __restrict__ out) // [16][64][64][96] bf16 CL
{
    constexpr int K = 5, PAD = 2, C = 3, H = 128, W = 128;
    constexpr int IT = 16 + K - 1;
    constexpr int DL = C * K * K;
    __shared__ float in_s[C][IT][IT + 1];
    __shared__ float w_s[DL][32];

    int bid = blockIdx.x;
    int tx = bid & 7; bid >>= 3;
    int ty = bid & 7; bid >>= 3;
    int ot = bid % 3; int b = bid / 3;
    int tid = threadIdx.x;
    int sp = tid & 63, og = tid >> 6;
    int sy = sp >> 3, sx = sp & 7;
    int o0 = ot * 32, y0 = ty * 16, x0 = tx * 16;
    const float* inb = in + (size_t)b * C * H * W;

    float acc[8][2][2];
    #pragma unroll
    for (int r = 0; r < 8; ++r)
        acc[r][0][0] = acc[r][0][1] = acc[r][1][0] = acc[r][1][1] = 0.f;

    for (int idx = tid; idx < C * IT * IT; idx += 256) {
        int ch = idx / (IT * IT), rem = idx - ch * (IT * IT);
        int iy = rem / IT, ix = rem - iy * IT;
        int y = y0 - PAD + iy, x = x0 - PAD + ix;
        float v = 0.f;
        if (y >= 0 && y < H && x >= 0 && x < W)
            v = inb[(size_t)ch * H * W + y * W + x];
        in_s[ch][iy][ix] = v;
    }
    for (int idx = tid; idx < DL * 32; idx += 256) {
        int dl = idx >> 5, ol = idx & 31;
        w_s[dl][ol] = w[(size_t)(o0 + ol) * DL + dl];
    }
    __syncthreads();
    for (int c = 0; c < C; ++c) {
        #pragma unroll
        for (int ki = 0; ki < K; ++ki) {
            #pragma unroll
            for (int kj = 0; kj < K; ++kj) {
                int dl = c * K * K + ki * K + kj;
                float i00 = in_s[c][2 * sy + ki][2 * sx + kj];
                float i01 = in_s[c][2 * sy + ki][2 * sx + kj + 1];
                float i10 = in_s[c][2 * sy + 1 + ki][2 * sx + kj];
                float i11 = in_s[c][2 * sy + 1 + ki][2 * sx + kj + 1];
                #pragma unroll
                for (int r = 0; r < 8; ++r) {
                    float wv = w_s[dl][og * 8 + r];
                    acc[r][0][0] += wv * i00;
                    acc[r][0][1] += wv * i01;
                    acc[r][1][0] += wv * i10;
                    acc[r][1][1] += wv * i11;
                }
            }
        }
    }

    float stdv = stdp[0], bias = biasp[0];
    float inv2s2 = 1.f / (2.f * stdv * stdv);
    float p[2][2];
    #pragma unroll
    for (int dy = 0; dy < 2; ++dy)
        #pragma unroll
        for (int dx = 0; dx < 2; ++dx)
            p[dy][dx] = pn[(size_t)b * H * W + (size_t)(y0 + 2 * sy + dy) * W + (x0 + 2 * sx + dx)];

    float a0 = alphap[0], a1 = alphap[1], a2 = alphap[2], a3 = alphap[3];
    unsigned short res[8];
    #pragma unroll
    for (int r = 0; r < 8; ++r) {
        int o = o0 + og * 8 + r;
        float wno = wn[o];
        float sfm = 0.f;
        #pragma unroll
        for (int dy = 0; dy < 2; ++dy)
            #pragma unroll
            for (int dx = 0; dx < 2; ++dx) {
                float d2 = fmaxf(p[dy][dx] + wno - 2.f * acc[r][dy][dx], 0.f);
                float g = __expf(-d2 * inv2s2);
                g = (g >= bias) ? g : 0.f;
                float al = (dy == 0) ? (dx == 0 ? a0 : a1) : (dx == 0 ? a2 : a3);
                sfm += al * g;
            }
        res[r] = f2bf(0.25f * sfm);
    }
    int yo = ty * 8 + sy, xo = tx * 8 + sx;
    bf16x8 pk;
    #pragma unroll
    for (int r = 0; r < 8; ++r) pk[r] = (short)res[r];
    *(bf16x8*)&out[(((size_t)b * 64 + yo) * 64 + xo) * 96 + o0 + og * 8] = pk;
}

// ---------- conv2: MFMA bf16. in [16][64][64][96] CL bf16, wt [192][25*96] bf16 ----------
// Block 4 waves (2x2): BM=96 o (wave_m: 48 each, 3 m-tiles), BN=128 px (16x8; wave_n: x-half)
__launch_bounds__(256, 2)
__global__ void conv2_mfma(const unsigned short* __restrict__ hin,
                           const unsigned short* __restrict__ wt,
                           const float* __restrict__ pn, const float* __restrict__ wn,
                           const float* __restrict__ stdp, const float* __restrict__ biasp,
                           const float* __restrict__ alphap,
                           unsigned short* __restrict__ hout) // [16][32][32][192] CL bf16
{
    __shared__ unsigned short in_s[12 * 20 * 96]; // 46080 B
    __shared__ unsigned short w_s[96 * 96];       // 18432 B

    int bid = blockIdx.x;
    int xt = bid & 3; bid >>= 2;
    int yt = bid & 7; bid >>= 3;
    int ot = bid & 1; int b = bid >> 1;
    int x0 = xt * 16, y0 = yt * 8, o0 = ot * 96;
    int tid = threadIdx.x;
    int lane = tid & 63, wid = tid >> 6;
    int wave_m = wid >> 1, wave_n = wid & 1;
    int col = lane & 15, kg = lane >> 4;

    // stage input tile [12 rows][20 cols][96 c]
    #pragma unroll
    for (int it = 0; it < 12; ++it) {
        int idx = tid + it * 256;
        if (idx < 2880) {
            int px = idx / 12, ch = idx - px * 12;
            int iy = px / 20, ix = px - iy * 20;
            int gy = y0 - 2 + iy, gx = x0 - 2 + ix;
            bf16x8 v = {0, 0, 0, 0, 0, 0, 0, 0};
            if (gy >= 0 && gy < 64 && gx >= 0 && gx < 64)
                v = *(const bf16x8*)&hin[(((size_t)b * 64 + gy) * 64 + gx) * 96 + ch * 8];
            *(bf16x8*)&in_s[idx * 8] = v;
        }
    }
    // stage tap-0 weights [96 o][96 c]
    #pragma unroll
    for (int it = 0; it < 5; ++it) {
        int idx = tid + it * 256;
        if (idx < 1152) {
            int row = idx / 12, ch = idx - row * 12;
            *(bf16x8*)&w_s[idx * 8] =
                *(const bf16x8*)&wt[(size_t)(o0 + row) * 2400 + ch * 8];
        }
    }
    __syncthreads();

    f32x4 acc[3][4];
    #pragma unroll
    for (int mt = 0; mt < 3; ++mt)
        #pragma unroll
        for (int nt = 0; nt < 4; ++nt) acc[mt][nt] = (f32x4){0.f, 0.f, 0.f, 0.f};

    for (int tap = 0; tap < 25; ++tap) {
        int ki = tap / 5, kj = tap - ki * 5;
        // prefetch next tap's weights into regs
        bf16x8 wreg[5];
        if (tap < 24) {
            #pragma unroll
            for (int it = 0; it < 5; ++it) {
                int idx = tid + it * 256;
                if (idx < 1152) {
                    int row = idx / 12, ch = idx - row * 12;
                    wreg[it] = *(const bf16x8*)&wt[(size_t)(o0 + row) * 2400 + (tap + 1) * 96 + ch * 8];
                }
            }
        }
        #pragma unroll
        for (int ks = 0; ks < 3; ++ks) {
            int c0 = ks * 32 + kg * 8;
            bf16x8 afrag[3], bfrag[4];
            #pragma unroll
            for (int mt = 0; mt < 3; ++mt)
                afrag[mt] = *(const bf16x8*)&w_s[(wave_m * 48 + mt * 16 + col) * 96 + c0];
            #pragma unroll
            for (int nt = 0; nt < 4; ++nt) {
                int yy = 2 * nt + (col >> 3) + ki;
                int xx = wave_n * 8 + (col & 7) + kj;
                bfrag[nt] = *(const bf16x8*)&in_s[(yy * 20 + xx) * 96 + c0];
            }
            #pragma unroll
            for (int mt = 0; mt < 3; ++mt)
                #pragma unroll
                for (int nt = 0; nt < 4; ++nt)
                    acc[mt][nt] = __builtin_amdgcn_mfma_f32_16x16x32_bf16(
                        afrag[mt], bfrag[nt], acc[mt][nt], 0, 0, 0);
        }
        __syncthreads();
        if (tap < 24) {
            #pragma unroll
            for (int it = 0; it < 5; ++it) {
                int idx = tid + it * 256;
                if (idx < 1152) *(bf16x8*)&w_s[idx * 8] = wreg[it];
            }
        }
        __syncthreads();
    }

    // epilogue: d2 -> gauss -> crelu -> alpha-weighted 2x2 mean pool -> bf16 CL
    float stdv = stdp[0], biasv = biasp[0];
    float inv2s2 = 1.f / (2.f * stdv * stdv);
    float a_own = alphap[(col >> 3) * 2 + (col & 1)];
    #pragma unroll
    for (int nt = 0; nt < 4; ++nt) {
        int y = y0 + 2 * nt + (col >> 3);
        int x = x0 + wave_n * 8 + (col & 7);
        float pnv = pn[((size_t)b * 64 + y) * 64 + x];
        int yo = (y0 >> 1) + nt;
        int xo = x >> 1;
        #pragma unroll
        for (int mt = 0; mt < 3; ++mt) {
            int ob = o0 + wave_m * 48 + mt * 16 + (kg << 2);
            unsigned short res[4];
            #pragma unroll
            for (int r = 0; r < 4; ++r) {
                float d2 = fmaxf(pnv + wn[ob + r] - 2.f * acc[mt][nt][r], 0.f);
                float g = __expf(-d2 * inv2s2);
                g = (g >= biasv) ? g : 0.f;
                g *= a_own;
                g += __shfl_xor(g, 1);
                g += __shfl_xor(g, 8);
                res[r] = f2bf(0.25f * g);
            }
            if (((col & 1) == 0) && ((col & 8) == 0)) {
                bf16x8 dummy; // pack 4 ushort -> 8B
                ushort4 pk = make_ushort4(res[0], res[1], res[2], res[3]);
                *(ushort4*)&hout[(((size_t)b * 32 + yo) * 32 + xo) * 192 + ob] = pk;
                (void)dummy;
            }
        }
    }
}

// ---------- conv3: MFMA bf16, no sfm. in [16][32][32][192] CL bf16, wt [384][9*192] ----------
// Block 4 waves (2x2): BM=96 o (wave_m), BN=64 px (8x8; wave_n: y-half of 4 rows)
__launch_bounds__(256, 2)
__global__ void conv3_mfma(const unsigned short* __restrict__ hin,
                           const unsigned short* __restrict__ wt,
                           const float* __restrict__ pn, const float* __restrict__ wn,
                           const float* __restrict__ stdp, const float* __restrict__ biasp,
                           float* __restrict__ hout) // [16][384][32][32] fp32 CF
{
    __shared__ unsigned short in_s[10 * 10 * 200]; // 40000 B (stride 200 = 100 dw == 4 mod 32)
    __shared__ unsigned short w_s[96 * 200];       // 38400 B

    int bid = blockIdx.x;
    int xt = bid & 3; bid >>= 2;
    int yt = bid & 3; bid >>= 2;
    int ot = bid & 3; int b = bid >> 2;
    int x0 = xt * 8, y0 = yt * 8, o0 = ot * 96;
    int tid = threadIdx.x;
    int lane = tid & 63, wid = tid >> 6;
    int wave_m = wid >> 1, wave_n = wid & 1;
    int col = lane & 15, kg = lane >> 4;

    // stage input tile [10][10][200] (last 8 ushort of each pixel = zero pad)
    #pragma unroll
    for (int it = 0; it < 10; ++it) {
        int idx = tid + it * 256;
        if (idx < 2500) {
            int px = idx / 25, ch = idx - px * 25;
            int iy = px / 10, ix = px - iy * 10;
            int gy = y0 - 1 + iy, gx = x0 - 1 + ix;
            bf16x8 v = {0, 0, 0, 0, 0, 0, 0, 0};
            if (ch < 24 && gy >= 0 && gy < 32 && gx >= 0 && gx < 32)
                v = *(const bf16x8*)&hin[(((size_t)b * 32 + gy) * 32 + gx) * 192 + ch * 8];
            *(bf16x8*)&in_s[idx * 8] = v;
        }
    }
    // stage tap-0 weights [96][200]
    #pragma unroll
    for (int it = 0; it < 10; ++it) {
        int idx = tid + it * 256;
        if (idx < 2400) {
            int row = idx / 25, ch = idx - row * 25;
            bf16x8 v = {0, 0, 0, 0, 0, 0, 0, 0};
            if (ch < 24)
                v = *(const bf16x8*)&wt[(size_t)(o0 + row) * 1728 + ch * 8];
            *(bf16x8*)&w_s[idx * 8] = v;
        }
    }
    __syncthreads();

    f32x4 acc[3][2];
    #pragma unroll
    for (int mt = 0; mt < 3; ++mt)
        #pragma unroll
        for (int nt = 0; nt < 2; ++nt) acc[mt][nt] = (f32x4){0.f, 0.f, 0.f, 0.f};

    for (int tap = 0; tap < 9; ++tap) {
        int ki = tap / 3, kj = tap - ki * 3;
        bf16x8 wreg[10];
        if (tap < 8) {
            #pragma unroll
            for (int it = 0; it < 10; ++it) {
                int idx = tid + it * 256;
                if (idx < 2400) {
                    int row = idx / 25, ch = idx - row * 25;
                    bf16x8 v = {0, 0, 0, 0, 0, 0, 0, 0};
                    if (ch < 24)
                        v = *(const bf16x8*)&wt[(size_t)(o0 + row) * 1728 + (tap + 1) * 192 + ch * 8];
                    wreg[it] = v;
                }
            }
        }
        #pragma unroll
        for (int ks = 0; ks < 6; ++ks) {
            int c0 = ks * 32 + kg * 8;
            bf16x8 afrag[3], bfrag[2];
            #pragma unroll
            for (int mt = 0; mt < 3; ++mt)
                afrag[mt] = *(const bf16x8*)&w_s[(wave_m * 48 + mt * 16 + col) * 200 + c0];
            #pragma unroll
            for (int nt = 0; nt < 2; ++nt) {
                int yy = wave_n * 4 + 2 * nt + (col >> 3) + ki;
                int xx = (col & 7) + kj;
                bfrag[nt] = *(const bf16x8*)&in_s[(yy * 10 + xx) * 200 + c0];
            }
            #pragma unroll
            for (int mt = 0; mt < 3; ++mt)
                #pragma unroll
                for (int nt = 0; nt < 2; ++nt)
                    acc[mt][nt] = __builtin_amdgcn_mfma_f32_16x16x32_bf16(
                        afrag[mt], bfrag[nt], acc[mt][nt], 0, 0, 0);
        }
        __syncthreads();
        if (tap < 8) {
            #pragma unroll
            for (int it = 0; it < 10; ++it) {
                int idx = tid + it * 256;
                if (idx < 2400) *(bf16x8*)&w_s[idx * 8] = wreg[it];
            }
        }
        __syncthreads();
    }

    float stdv = stdp[0], biasv = biasp[0];
    float inv2s2 = 1.f / (2.f * stdv * stdv);
    #pragma unroll
    for (int nt = 0; nt < 2; ++nt) {
        int y = y0 + wave_n * 4 + 2 * nt + (col >> 3);
        int x = x0 + (col & 7);
        float pnv = pn[((size_t)b * 32 + y) * 32 + x];
        #pragma unroll
        for (int mt = 0; mt < 3; ++mt) {
            int ob = o0 + wave_m * 48 + mt * 16 + (kg << 2);
            #pragma unroll
            for (int r = 0; r < 4; ++r) {
                float d2 = fmaxf(pnv + wn[ob + r] - 2.f * acc[mt][nt][r], 0.f);
                float g = __expf(-d2 * inv2s2);
                g = (g >= biasv) ? g : 0.f;
                hout[(((size_t)b * 384 + ob + r) * 32 + y) * 32 + x] = g;
            }
        }
    }
}

// ---------- FC ----------
__launch_bounds__(256)
__global__ void fc_partial_kernel(const float* __restrict__ h3, const float* __restrict__ fw,
                                  float* __restrict__ partial) {
    const int KI = 384 * 32 * 32;
    int bid = blockIdx.x;
    int jt = bid / 96, ch = bid - jt * 96;
    int tid = threadIdx.x;
    int j0 = jt * 4;
    float acc[4][16];
    #pragma unroll
    for (int jj = 0; jj < 4; ++jj)
        #pragma unroll
        for (int b = 0; b < 16; ++b) acc[jj][b] = 0.f;
    int ibase = ch * 4096 + tid;
    for (int ii = 0; ii < 16; ++ii) {
        int i = ibase + ii * 256;
        float hv[16];
        #pragma unroll
        for (int b = 0; b < 16; ++b) hv[b] = h3[(size_t)b * KI + i];
        #pragma unroll
        for (int jj = 0; jj < 4; ++jj) {
            float wv = fw[(size_t)(j0 + jj) * KI + i];
            #pragma unroll
            for (int b = 0; b < 16; ++b) acc[jj][b] += wv * hv[b];
        }
    }
    __shared__ float red[4][64];
    int lane = tid & 63, wv_ = tid >> 6;
    #pragma unroll
    for (int jj = 0; jj < 4; ++jj)
        #pragma unroll
        for (int b = 0; b < 16; ++b) {
            float v = acc[jj][b];
            v += __shfl_down(v, 32); v += __shfl_down(v, 16); v += __shfl_down(v, 8);
            v += __shfl_down(v, 4);  v += __shfl_down(v, 2);  v += __shfl_down(v, 1);
            if (lane == 0) red[wv_][jj * 16 + b] = v;
        }
    __syncthreads();
    if (tid < 64)
        partial[(size_t)bid * 64 + tid] = red[0][tid] + red[1][tid] + red[2][tid] + red[3][tid];
}

__global__ void fc_final_kernel(const float* __restrict__ partial, const float* __restrict__ fb,
                                float* __restrict__ outp) {
    int t = blockIdx.x * TPB + threadIdx.x;
    if (t >= 1600) return;
    int b = t / 100, j = t - b * 100;
    int jt = j >> 2, jj = j & 3;
    float s = fb[j];
    for (int ch = 0; ch < 96; ++ch)
        s += partial[(size_t)(jt * 96 + ch) * 64 + jj * 16 + b];
    outp[t] = s;
}

// ---------- launch ----------
extern "C" void kernel_launch(void* const* d_in, const int* in_sizes, int n_in,
                              void* d_out, int out_size, void* d_ws, size_t ws_size,
                              hipStream_t stream) {
    const float* x      = (const float*)d_in[0];
    const float* w1     = (const float*)d_in[1];
    const float* std1   = (const float*)d_in[2];
    const float* bias1  = (const float*)d_in[3];
    const float* alpha1 = (const float*)d_in[4];
    const float* w2     = (const float*)d_in[5];
    const float* std2   = (const float*)d_in[6];
    const float* bias2  = (const float*)d_in[7];
    const float* alpha2 = (const float*)d_in[8];
    const float* w3     = (const float*)d_in[9];
    const float* std3   = (const float*)d_in[10];
    const float* bias3  = (const float*)d_in[11];
    const float* fc_w   = (const float*)d_in[12];
    const float* fc_b   = (const float*)d_in[13];
    float* out = (float*)d_out;
    float* ws  = (float*)d_ws;

    // ws layout (in floats)
    float* pn1   = ws;                  // 262144
    float* sbuf  = pn1 + 262144;        // 262144 (reused for all sq-sums)
    float* pn2   = sbuf + 262144;       // 65536
    float* pn3   = pn2 + 65536;         // 16384
    float* h3    = pn3 + 16384;         // 6291456
    float* fcp   = h3 + 6291456;        // 153600
    float* wn1   = fcp + 153600;        // 96
    float* wn2   = wn1 + 96;            // 192
    float* wn3   = wn2 + 192;           // 384 (+pad to 128-align)
    float* rest  = wn3 + 384 + 32;
    unsigned short* h1bf = (unsigned short*)rest;            // 6291456 ushort
    unsigned short* h2bf = h1bf + 6291456;                   // 3145728 ushort
    unsigned short* w2bf = h2bf + 3145728;                   // 460800 ushort
    unsigned short* w3bf = w2bf + 460800 + 32;               // 663552 ushort

    dim3 B(TPB);

    // ---- block 1: x[16,3,128,128] -> h1bf[16,64,64,96] ----
    sq_sum_kernel<<<dim3(16 * 16384 / TPB), B, 0, stream>>>(x, sbuf, 3, 16384);
    win_sum_kernel<5, 2><<<dim3(16 * 16384 / TPB), B, 0, stream>>>(sbuf, pn1, 128, 128);
    wn_kernel<<<dim3(96), dim3(64), 0, stream>>>(w1, wn1, 75);
    conv1_kernel<<<dim3(16 * 3 * 8 * 8), B, 0, stream>>>(
        x, w1, pn1, wn1, std1, bias1, alpha1, h1bf);

    // ---- block 2: h1bf -> h2bf[16,32,32,192] ----
    sq_cl_kernel<96><<<dim3(16 * 4096 / TPB), B, 0, stream>>>(h1bf, sbuf);
    win_sum_kernel<5, 2><<<dim3(16 * 4096 / TPB), B, 0, stream>>>(sbuf, pn2, 64, 64);
    wn_kernel<<<dim3(192), dim3(64), 0, stream>>>(w2, wn2, 2400);
    wt_reorder_kernel<<<dim3((192 * 2400 + TPB - 1) / TPB), B, 0, stream>>>(w2, w2bf, 192, 96, 25);
    conv2_mfma<<<dim3(16 * 2 * 8 * 4), B, 0, stream>>>(
        h1bf, w2bf, pn2, wn2, std2, bias2, alpha2, h2bf);

    // ---- block 3: h2bf -> h3[16,384,32,32] fp32 CF ----
    sq_cl_kernel<192><<<dim3(16 * 1024 / TPB), B, 0, stream>>>(h2bf, sbuf);
    win_sum_kernel<3, 1><<<dim3(16 * 1024 / TPB), B, 0, stream>>>(sbuf, pn3, 32, 32);
    wn_kernel<<<dim3(384), dim3(64), 0, stream>>>(w3, wn3, 1728);
    wt_reorder_kernel<<<dim3((384 * 1728 + TPB - 1) / TPB), B, 0, stream>>>(w3, w3bf, 384, 192, 9);
    conv3_mfma<<<dim3(16 * 4 * 4 * 4), B, 0, stream>>>(
        h2bf, w3bf, pn3, wn3, std3, bias3, h3);

    // ---- fc ----
    fc_partial_kernel<<<dim3(25 * 96), B, 0, stream>>>(h3, fc_w, fcp);
    fc_final_kernel<<<dim3((1600 + TPB - 1) / TPB), B, 0, stream>>>(fcp, fc_b, out);
}

// Round 3
// 269.809 us; speedup vs baseline: 5.0589x; 1.3230x over previous
//
#include <hip/hip_runtime.h>

#define TPB 256

typedef short bf16x8 __attribute__((ext_vector_type(8)));
typedef float f32x4 __attribute__((ext_vector_type(4)));

__device__ inline unsigned short f2bf(float f) {
    unsigned int u = __float_as_uint(f);
    unsigned int r = (u + 0x7fffu + ((u >> 16) & 1u)) >> 16;
    return (unsigned short)r;
}
__device__ inline float bf2f(unsigned short h) {
    return __uint_as_float(((unsigned int)h) << 16);
}

// ---------- small kernels ----------

__global__ void sq_sum_kernel(const float* __restrict__ src, float* __restrict__ dst,
                              int C, int HW) {
    int idx = blockIdx.x * TPB + threadIdx.x;
    int b = idx / HW, p = idx - b * HW;
    const float* s = src + (size_t)b * C * HW + p;
    float acc = 0.f;
    for (int c = 0; c < C; ++c) { float v = s[(size_t)c * HW]; acc += v * v; }
    dst[idx] = acc;
}

template<int C>
__global__ void sq_cl_kernel(const unsigned short* __restrict__ src, float* __restrict__ dst) {
    int idx = blockIdx.x * TPB + threadIdx.x;
    const unsigned short* s = src + (size_t)idx * C;
    float acc = 0.f;
    #pragma unroll
    for (int c = 0; c < C; c += 8) {
        bf16x8 v = *(const bf16x8*)&s[c];
        #pragma unroll
        for (int j = 0; j < 8; ++j) { float f = bf2f((unsigned short)v[j]); acc += f * f; }
    }
    dst[idx] = acc;
}

template<int K, int PAD>
__global__ void win_sum_kernel(const float* __restrict__ s, float* __restrict__ pn,
                               int H, int W) {
    int idx = blockIdx.x * TPB + threadIdx.x;
    int b = idx / (H * W); int rem = idx - b * H * W;
    int y = rem / W, x = rem - y * W;
    const float* sb = s + (size_t)b * H * W;
    float acc = 0.f;
    #pragma unroll
    for (int ki = 0; ki < K; ++ki) {
        int yy = y - PAD + ki;
        if (yy < 0 || yy >= H) continue;
        #pragma unroll
        for (int kj = 0; kj < K; ++kj) {
            int xx = x - PAD + kj;
            if (xx < 0 || xx >= W) continue;
            acc += sb[yy * W + xx];
        }
    }
    pn[idx] = acc;
}

__global__ void wn_kernel(const float* __restrict__ w, float* __restrict__ wn, int D) {
    int o = blockIdx.x;
    int lane = threadIdx.x;
    const float* row = w + (size_t)o * D;
    float acc = 0.f;
    for (int i = lane; i < D; i += 64) { float v = row[i]; acc += v * v; }
    #pragma unroll
    for (int off = 32; off >= 1; off >>= 1) acc += __shfl_down(acc, off);
    if (lane == 0) wn[o] = acc;
}

// reorder weights [O][C*KK] (c-major) -> bf16 [O][KK*C] (tap-major); for conv2/conv3
__global__ void wt_reorder_kernel(const float* __restrict__ w, unsigned short* __restrict__ wbf,
                                  int O, int C, int KK) {
    int idx = blockIdx.x * TPB + threadIdx.x;
    if (idx >= O * C * KK) return;
    int c = idx % C; int t = idx / C; int tap = t % KK; int o = t / KK;
    wbf[idx] = f2bf(w[((size_t)o * C + c) * KK + tap]);
}

// x [16,3,128,128] fp32 CF -> xbf [16][128][128][4] bf16 (c padded to 4 with 0)
__global__ void xbf_prep(const float* __restrict__ x, unsigned short* __restrict__ xbf) {
    int idx = blockIdx.x * TPB + threadIdx.x;  // 262144
    int b = idx >> 14, px = idx & 16383;
    const float* xb = x + (size_t)b * 3 * 16384 + px;
    ushort4 v;
    v.x = f2bf(xb[0]); v.y = f2bf(xb[16384]); v.z = f2bf(xb[32768]); v.w = 0;
    *(ushort4*)&xbf[(size_t)idx * 4] = v;
}

// w1 [96][75] (c*25 + ki*5+kj) -> w1r [96][136] bf16, d = tp*4+c,
// tp = ki*6+kj (rows padded to 6 taps, taps 30..33 zero), row padded 128->136
__global__ void wt1_reorder(const float* __restrict__ w1, unsigned short* __restrict__ w1r) {
    int idx = blockIdx.x * TPB + threadIdx.x;
    if (idx >= 96 * 136) return;
    int o = idx / 136, d = idx - o * 136;
    int tp = d >> 2, c = d & 3;
    float v = 0.f;
    if (tp < 30 && c < 3) {
        int ki = tp / 6, kj = tp - 6 * ki;
        if (kj < 5) v = w1[o * 75 + c * 25 + ki * 5 + kj];
    }
    w1r[idx] = f2bf(v);
}

// ---------- conv1: MFMA bf16, K=128 (32 taps x 4c) ----------
// Block: 16x16 px tile, all 96 o. 4 waves; wave w: rows y0+4w..y0+4w+3 (4 n-frags).
__launch_bounds__(256, 2)
__global__ void conv1_mfma(const unsigned short* __restrict__ xbf,
                           const unsigned short* __restrict__ w1r,
                           const float* __restrict__ pn, const float* __restrict__ wn,
                           const float* __restrict__ stdp, const float* __restrict__ biasp,
                           const float* __restrict__ alphap,
                           unsigned short* __restrict__ out) // [16][64][64][96] bf16 CL
{
    __shared__ unsigned short in_s[22 * 20 * 4]; // rows 0..20 staged
    __shared__ unsigned short w_s[96 * 136];     // 26112 B

    int bid = blockIdx.x;
    int tx = bid & 7; bid >>= 3;
    int ty = bid & 7; bid >>= 3;
    int b = bid;
    int x0 = tx * 16, y0 = ty * 16;
    int tid = threadIdx.x;
    int lane = tid & 63, wv = tid >> 6;
    int col = lane & 15, kg = lane >> 4;

    // stage input rows 0..20 (gy = y0-2 .. y0+18)
    for (int idx = tid; idx < 21 * 20; idx += 256) {
        int py = idx / 20, px = idx - py * 20;
        int gy = y0 - 2 + py, gx = x0 - 2 + px;
        ushort4 v = make_ushort4(0, 0, 0, 0);
        if (gy >= 0 && gy < 128 && gx >= 0 && gx < 128)
            v = *(const ushort4*)&xbf[(((size_t)b * 128 + gy) * 128 + gx) * 4];
        *(ushort4*)&in_s[idx * 4] = v;
    }
    // stage weights (96*136 = 1632 chunks of 8)
    for (int idx = tid; idx < 1632; idx += 256)
        *(bf16x8*)&w_s[idx * 8] = *(const bf16x8*)&w1r[idx * 8];
    __syncthreads();

    f32x4 acc[6][4];
    #pragma unroll
    for (int mt = 0; mt < 6; ++mt)
        #pragma unroll
        for (int n = 0; n < 4; ++n) acc[mt][n] = (f32x4){0.f, 0.f, 0.f, 0.f};

    #pragma unroll
    for (int ks = 0; ks < 4; ++ks) {
        int tap0 = ks * 8 + kg * 2;           // even
        int ki = tap0 / 6, kj = tap0 - 6 * ki; // kj in {0,2,4}
        bf16x8 bfrag[4];
        #pragma unroll
        for (int n = 0; n < 4; ++n) {
            int row = wv * 4 + n + ki;
            int ix = col + kj;
            const unsigned short* p = &in_s[(row * 20 + ix) * 4];
            union { bf16x8 v; uint2 u[2]; } tmp;
            tmp.u[0] = *(const uint2*)p;
            tmp.u[1] = *(const uint2*)(p + 4);
            bfrag[n] = tmp.v;
        }
        bf16x8 afrag[6];
        #pragma unroll
        for (int mt = 0; mt < 6; ++mt)
            afrag[mt] = *(const bf16x8*)&w_s[(mt * 16 + col) * 136 + ks * 32 + kg * 8];
        #pragma unroll
        for (int mt = 0; mt < 6; ++mt)
            #pragma unroll
            for (int n = 0; n < 4; ++n)
                acc[mt][n] = __builtin_amdgcn_mfma_f32_16x16x32_bf16(
                    afrag[mt], bfrag[n], acc[mt][n], 0, 0, 0);
    }

    // epilogue: gauss -> crelu -> alpha-pool 2x2 -> bf16 CL
    float stdv = stdp[0], biasv = biasp[0];
    float inv2s2 = 1.f / (2.f * stdv * stdv);
    float a00 = alphap[0], a01 = alphap[1], a10 = alphap[2], a11 = alphap[3];
    int dx = col & 1;
    float ax0 = dx ? a01 : a00;
    float ax1 = dx ? a11 : a10;
    float pnv[4];
    #pragma unroll
    for (int n = 0; n < 4; ++n)
        pnv[n] = pn[((size_t)b * 128 + (y0 + wv * 4 + n)) * 128 + x0 + col];

    #pragma unroll
    for (int mt = 0; mt < 6; ++mt) {
        #pragma unroll
        for (int p2 = 0; p2 < 2; ++p2) {
            unsigned short res[4];
            #pragma unroll
            for (int r = 0; r < 4; ++r) {
                int o = mt * 16 + kg * 4 + r;
                float wno = wn[o];
                float d20 = fmaxf(pnv[2 * p2] + wno - 2.f * acc[mt][2 * p2][r], 0.f);
                float d21 = fmaxf(pnv[2 * p2 + 1] + wno - 2.f * acc[mt][2 * p2 + 1][r], 0.f);
                float g0 = __expf(-d20 * inv2s2);
                float g1 = __expf(-d21 * inv2s2);
                g0 = (g0 >= biasv) ? g0 : 0.f;
                g1 = (g1 >= biasv) ? g1 : 0.f;
                float s = ax0 * g0 + ax1 * g1;
                s += __shfl_xor(s, 1);
                res[r] = f2bf(0.25f * s);
            }
            if (dx == 0) {
                int yo = ty * 8 + wv * 2 + p2, xo = tx * 8 + (col >> 1);
                *(ushort4*)&out[(((size_t)b * 64 + yo) * 64 + xo) * 96 + mt * 16 + kg * 4] =
                    make_ushort4(res[0], res[1], res[2], res[3]);
            }
        }
    }
}

// ---------- conv2: MFMA bf16 (unchanged) ----------
__launch_bounds__(256, 2)
__global__ void conv2_mfma(const unsigned short* __restrict__ hin,
                           const unsigned short* __restrict__ wt,
                           const float* __restrict__ pn, const float* __restrict__ wn,
                           const float* __restrict__ stdp, const float* __restrict__ biasp,
                           const float* __restrict__ alphap,
                           unsigned short* __restrict__ hout) // [16][32][32][192] CL bf16
{
    __shared__ unsigned short in_s[12 * 20 * 96];
    __shared__ unsigned short w_s[96 * 96];

    int bid = blockIdx.x;
    int xt = bid & 3; bid >>= 2;
    int yt = bid & 7; bid >>= 3;
    int ot = bid & 1; int b = bid >> 1;
    int x0 = xt * 16, y0 = yt * 8, o0 = ot * 96;
    int tid = threadIdx.x;
    int lane = tid & 63, wid = tid >> 6;
    int wave_m = wid >> 1, wave_n = wid & 1;
    int col = lane & 15, kg = lane >> 4;

    #pragma unroll
    for (int it = 0; it < 12; ++it) {
        int idx = tid + it * 256;
        if (idx < 2880) {
            int px = idx / 12, ch = idx - px * 12;
            int iy = px / 20, ix = px - iy * 20;
            int gy = y0 - 2 + iy, gx = x0 - 2 + ix;
            bf16x8 v = {0, 0, 0, 0, 0, 0, 0, 0};
            if (gy >= 0 && gy < 64 && gx >= 0 && gx < 64)
                v = *(const bf16x8*)&hin[(((size_t)b * 64 + gy) * 64 + gx) * 96 + ch * 8];
            *(bf16x8*)&in_s[idx * 8] = v;
        }
    }
    #pragma unroll
    for (int it = 0; it < 5; ++it) {
        int idx = tid + it * 256;
        if (idx < 1152) {
            int row = idx / 12, ch = idx - row * 12;
            *(bf16x8*)&w_s[idx * 8] =
                *(const bf16x8*)&wt[(size_t)(o0 + row) * 2400 + ch * 8];
        }
    }
    __syncthreads();

    f32x4 acc[3][4];
    #pragma unroll
    for (int mt = 0; mt < 3; ++mt)
        #pragma unroll
        for (int nt = 0; nt < 4; ++nt) acc[mt][nt] = (f32x4){0.f, 0.f, 0.f, 0.f};

    for (int tap = 0; tap < 25; ++tap) {
        int ki = tap / 5, kj = tap - ki * 5;
        bf16x8 wreg[5];
        if (tap < 24) {
            #pragma unroll
            for (int it = 0; it < 5; ++it) {
                int idx = tid + it * 256;
                if (idx < 1152) {
                    int row = idx / 12, ch = idx - row * 12;
                    wreg[it] = *(const bf16x8*)&wt[(size_t)(o0 + row) * 2400 + (tap + 1) * 96 + ch * 8];
                }
            }
        }
        #pragma unroll
        for (int ks = 0; ks < 3; ++ks) {
            int c0 = ks * 32 + kg * 8;
            bf16x8 afrag[3], bfrag[4];
            #pragma unroll
            for (int mt = 0; mt < 3; ++mt)
                afrag[mt] = *(const bf16x8*)&w_s[(wave_m * 48 + mt * 16 + col) * 96 + c0];
            #pragma unroll
            for (int nt = 0; nt < 4; ++nt) {
                int yy = 2 * nt + (col >> 3) + ki;
                int xx = wave_n * 8 + (col & 7) + kj;
                bfrag[nt] = *(const bf16x8*)&in_s[(yy * 20 + xx) * 96 + c0];
            }
            #pragma unroll
            for (int mt = 0; mt < 3; ++mt)
                #pragma unroll
                for (int nt = 0; nt < 4; ++nt)
                    acc[mt][nt] = __builtin_amdgcn_mfma_f32_16x16x32_bf16(
                        afrag[mt], bfrag[nt], acc[mt][nt], 0, 0, 0);
        }
        __syncthreads();
        if (tap < 24) {
            #pragma unroll
            for (int it = 0; it < 5; ++it) {
                int idx = tid + it * 256;
                if (idx < 1152) *(bf16x8*)&w_s[idx * 8] = wreg[it];
            }
        }
        __syncthreads();
    }

    float stdv = stdp[0], biasv = biasp[0];
    float inv2s2 = 1.f / (2.f * stdv * stdv);
    float a_own = alphap[(col >> 3) * 2 + (col & 1)];
    #pragma unroll
    for (int nt = 0; nt < 4; ++nt) {
        int y = y0 + 2 * nt + (col >> 3);
        int x = x0 + wave_n * 8 + (col & 7);
        float pnv = pn[((size_t)b * 64 + y) * 64 + x];
        int yo = (y0 >> 1) + nt;
        int xo = x >> 1;
        #pragma unroll
        for (int mt = 0; mt < 3; ++mt) {
            int ob = o0 + wave_m * 48 + mt * 16 + (kg << 2);
            unsigned short res[4];
            #pragma unroll
            for (int r = 0; r < 4; ++r) {
                float d2 = fmaxf(pnv + wn[ob + r] - 2.f * acc[mt][nt][r], 0.f);
                float g = __expf(-d2 * inv2s2);
                g = (g >= biasv) ? g : 0.f;
                g *= a_own;
                g += __shfl_xor(g, 1);
                g += __shfl_xor(g, 8);
                res[r] = f2bf(0.25f * g);
            }
            if (((col & 1) == 0) && ((col & 8) == 0)) {
                *(ushort4*)&hout[(((size_t)b * 32 + yo) * 32 + xo) * 192 + ob] =
                    make_ushort4(res[0], res[1], res[2], res[3]);
            }
        }
    }
}

// ---------- conv3: MFMA bf16 -> h3 bf16 CF flat ----------
__launch_bounds__(256, 2)
__global__ void conv3_mfma(const unsigned short* __restrict__ hin,
                           const unsigned short* __restrict__ wt,
                           const float* __restrict__ pn, const float* __restrict__ wn,
                           const float* __restrict__ stdp, const float* __restrict__ biasp,
                           unsigned short* __restrict__ hout) // [16][384*32*32] bf16 CF
{
    __shared__ unsigned short in_s[10 * 10 * 200];
    __shared__ unsigned short w_s[96 * 200];

    int bid = blockIdx.x;
    int xt = bid & 3; bid >>= 2;
    int yt = bid & 3; bid >>= 2;
    int ot = bid & 3; int b = bid >> 2;
    int x0 = xt * 8, y0 = yt * 8, o0 = ot * 96;
    int tid = threadIdx.x;
    int lane = tid & 63, wid = tid >> 6;
    int wave_m = wid >> 1, wave_n = wid & 1;
    int col = lane & 15, kg = lane >> 4;

    #pragma unroll
    for (int it = 0; it < 10; ++it) {
        int idx = tid + it * 256;
        if (idx < 2500) {
            int px = idx / 25, ch = idx - px * 25;
            int iy = px / 10, ix = px - iy * 10;
            int gy = y0 - 1 + iy, gx = x0 - 1 + ix;
            bf16x8 v = {0, 0, 0, 0, 0, 0, 0, 0};
            if (ch < 24 && gy >= 0 && gy < 32 && gx >= 0 && gx < 32)
                v = *(const bf16x8*)&hin[(((size_t)b * 32 + gy) * 32 + gx) * 192 + ch * 8];
            *(bf16x8*)&in_s[idx * 8] = v;
        }
    }
    #pragma unroll
    for (int it = 0; it < 10; ++it) {
        int idx = tid + it * 256;
        if (idx < 2400) {
            int row = idx / 25, ch = idx - row * 25;
            bf16x8 v = {0, 0, 0, 0, 0, 0, 0, 0};
            if (ch < 24)
                v = *(const bf16x8*)&wt[(size_t)(o0 + row) * 1728 + ch * 8];
            *(bf16x8*)&w_s[idx * 8] = v;
        }
    }
    __syncthreads();

    f32x4 acc[3][2];
    #pragma unroll
    for (int mt = 0; mt < 3; ++mt)
        #pragma unroll
        for (int nt = 0; nt < 2; ++nt) acc[mt][nt] = (f32x4){0.f, 0.f, 0.f, 0.f};

    for (int tap = 0; tap < 9; ++tap) {
        int ki = tap / 3, kj = tap - ki * 3;
        bf16x8 wreg[10];
        if (tap < 8) {
            #pragma unroll
            for (int it = 0; it < 10; ++it) {
                int idx = tid + it * 256;
                if (idx < 2400) {
                    int row = idx / 25, ch = idx - row * 25;
                    bf16x8 v = {0, 0, 0, 0, 0, 0, 0, 0};
                    if (ch < 24)
                        v = *(const bf16x8*)&wt[(size_t)(o0 + row) * 1728 + (tap + 1) * 192 + ch * 8];
                    wreg[it] = v;
                }
            }
        }
        #pragma unroll
        for (int ks = 0; ks < 6; ++ks) {
            int c0 = ks * 32 + kg * 8;
            bf16x8 afrag[3], bfrag[2];
            #pragma unroll
            for (int mt = 0; mt < 3; ++mt)
                afrag[mt] = *(const bf16x8*)&w_s[(wave_m * 48 + mt * 16 + col) * 200 + c0];
            #pragma unroll
            for (int nt = 0; nt < 2; ++nt) {
                int yy = wave_n * 4 + 2 * nt + (col >> 3) + ki;
                int xx = (col & 7) + kj;
                bfrag[nt] = *(const bf16x8*)&in_s[(yy * 10 + xx) * 200 + c0];
            }
            #pragma unroll
            for (int mt = 0; mt < 3; ++mt)
                #pragma unroll
                for (int nt = 0; nt < 2; ++nt)
                    acc[mt][nt] = __builtin_amdgcn_mfma_f32_16x16x32_bf16(
                        afrag[mt], bfrag[nt], acc[mt][nt], 0, 0, 0);
        }
        __syncthreads();
        if (tap < 8) {
            #pragma unroll
            for (int it = 0; it < 10; ++it) {
                int idx = tid + it * 256;
                if (idx < 2400) *(bf16x8*)&w_s[idx * 8] = wreg[it];
            }
        }
        __syncthreads();
    }

    float stdv = stdp[0], biasv = biasp[0];
    float inv2s2 = 1.f / (2.f * stdv * stdv);
    #pragma unroll
    for (int nt = 0; nt < 2; ++nt) {
        int y = y0 + wave_n * 4 + 2 * nt + (col >> 3);
        int x = x0 + (col & 7);
        float pnv = pn[((size_t)b * 32 + y) * 32 + x];
        #pragma unroll
        for (int mt = 0; mt < 3; ++mt) {
            int ob = o0 + wave_m * 48 + mt * 16 + (kg << 2);
            #pragma unroll
            for (int r = 0; r < 4; ++r) {
                float d2 = fmaxf(pnv + wn[ob + r] - 2.f * acc[mt][nt][r], 0.f);
                float g = __expf(-d2 * inv2s2);
                g = (g >= biasv) ? g : 0.f;
                hout[((size_t)b * 384 + ob + r) * 1024 + y * 32 + x] = f2bf(g);
            }
        }
    }
}

// ---------- FC: MFMA over K-chunks ----------
// Block ch (768): i-chunk of 512. Stage h3 chunk + 16 fc_w rows/jt as bf16 in LDS.
// M=16 j (112 padded, 7 jt), N=16 b, K=512 split over 4 waves.
__launch_bounds__(256, 4)
__global__ void fc_mfma(const unsigned short* __restrict__ h3bf,
                        const float* __restrict__ fw,
                        float* __restrict__ fcp) // [768][112][16]
{
    __shared__ unsigned short h3s[16 * 520];
    __shared__ unsigned short fws[16 * 520];
    __shared__ float red[4][16][16];
    const size_t KI = 393216;
    int ch = blockIdx.x;
    int i0 = ch * 512;
    int tid = threadIdx.x;
    int lane = tid & 63, wv = tid >> 6;
    int col = lane & 15, kg = lane >> 4;

    #pragma unroll
    for (int it = 0; it < 4; ++it) {
        int c = tid + it * 256;            // 1024 chunks of 8 ushorts
        int b = c >> 6, off = (c & 63) * 8;
        *(bf16x8*)&h3s[b * 520 + off] = *(const bf16x8*)&h3bf[(size_t)b * KI + i0 + off];
    }

    for (int jt = 0; jt < 7; ++jt) {
        int j0 = jt * 16;
        __syncthreads();
        #pragma unroll
        for (int it = 0; it < 8; ++it) {
            int c = tid + it * 256;        // 2048 float4 chunks
            int row = c >> 7, off4 = (c & 127) * 4;
            float4 v = make_float4(0.f, 0.f, 0.f, 0.f);
            int j = j0 + row;
            if (j < 100) v = *(const float4*)&fw[(size_t)j * KI + i0 + off4];
            *(ushort4*)&fws[row * 520 + off4] =
                make_ushort4(f2bf(v.x), f2bf(v.y), f2bf(v.z), f2bf(v.w));
        }
        __syncthreads();
        f32x4 acc = (f32x4){0.f, 0.f, 0.f, 0.f};
        #pragma unroll
        for (int s = 0; s < 4; ++s) {
            int k = wv * 128 + s * 32 + kg * 8;
            bf16x8 af = *(const bf16x8*)&fws[col * 520 + k];
            bf16x8 bg = *(const bf16x8*)&h3s[col * 520 + k];
            acc = __builtin_amdgcn_mfma_f32_16x16x32_bf16(af, bg, acc, 0, 0, 0);
        }
        #pragma unroll
        for (int r = 0; r < 4; ++r) red[wv][kg * 4 + r][col] = acc[r];
        __syncthreads();
        int j = tid >> 4, bb = tid & 15;
        float s = red[0][j][bb] + red[1][j][bb] + red[2][j][bb] + red[3][j][bb];
        fcp[((size_t)ch * 112 + j0 + j) * 16 + bb] = s;
    }
}

// out[b][j] = fb[j] + sum_ch fcp[ch][j][b]; 100 blocks x 1 wave
__global__ void fc_final(const float* __restrict__ fcp, const float* __restrict__ fb,
                         float* __restrict__ outp) {
    int j = blockIdx.x;
    int lane = threadIdx.x;
    float acc[16];
    #pragma unroll
    for (int b = 0; b < 16; ++b) acc[b] = 0.f;
    for (int ch = lane; ch < 768; ch += 64) {
        const float* p = &fcp[((size_t)ch * 112 + j) * 16];
        #pragma unroll
        for (int b = 0; b < 16; ++b) acc[b] += p[b];
    }
    #pragma unroll
    for (int off = 32; off >= 1; off >>= 1)
        #pragma unroll
        for (int b = 0; b < 16; ++b) acc[b] += __shfl_down(acc[b], off);
    if (lane == 0) {
        float bj = fb[j];
        #pragma unroll
        for (int b = 0; b < 16; ++b) outp[b * 100 + j] = bj + acc[b];
    }
}

// ---------- launch ----------
extern "C" void kernel_launch(void* const* d_in, const int* in_sizes, int n_in,
                              void* d_out, int out_size, void* d_ws, size_t ws_size,
                              hipStream_t stream) {
    const float* x      = (const float*)d_in[0];
    const float* w1     = (const float*)d_in[1];
    const float* std1   = (const float*)d_in[2];
    const float* bias1  = (const float*)d_in[3];
    const float* alpha1 = (const float*)d_in[4];
    const float* w2     = (const float*)d_in[5];
    const float* std2   = (const float*)d_in[6];
    const float* bias2  = (const float*)d_in[7];
    const float* alpha2 = (const float*)d_in[8];
    const float* w3     = (const float*)d_in[9];
    const float* std3   = (const float*)d_in[10];
    const float* bias3  = (const float*)d_in[11];
    const float* fc_w   = (const float*)d_in[12];
    const float* fc_b   = (const float*)d_in[13];
    float* out = (float*)d_out;
    float* ws  = (float*)d_ws;

    // float region
    float* pn1   = ws;                  // 262144
    float* sbuf  = pn1 + 262144;        // 262144
    float* pn2   = sbuf + 262144;       // 65536
    float* pn3   = pn2 + 65536;         // 16384
    float* fcp   = pn3 + 16384;         // 768*112*16 = 1376256
    float* wn1   = fcp + 1376256;       // 96
    float* wn2   = wn1 + 96;            // 192
    float* wn3   = wn2 + 192;           // 384
    float* rest  = wn3 + 384 + 32;      // pad, 16B aligned
    // ushort region
    unsigned short* h1bf = (unsigned short*)rest;  // 6291456
    unsigned short* h2bf = h1bf + 6291456;         // 3145728
    unsigned short* w2bf = h2bf + 3145728;         // 460800
    unsigned short* w3bf = w2bf + 460800;          // 663552
    unsigned short* h3bf = w3bf + 663552;          // 6291456
    unsigned short* xbf  = h3bf + 6291456;         // 1048576
    unsigned short* w1r  = xbf + 1048576;          // 13056

    dim3 B(TPB);

    // ---- block 1 ----
    xbf_prep<<<dim3(1024), B, 0, stream>>>(x, xbf);
    wt1_reorder<<<dim3(51), B, 0, stream>>>(w1, w1r);
    sq_sum_kernel<<<dim3(16 * 16384 / TPB), B, 0, stream>>>(x, sbuf, 3, 16384);
    win_sum_kernel<5, 2><<<dim3(16 * 16384 / TPB), B, 0, stream>>>(sbuf, pn1, 128, 128);
    wn_kernel<<<dim3(96), dim3(64), 0, stream>>>(w1, wn1, 75);
    conv1_mfma<<<dim3(1024), B, 0, stream>>>(xbf, w1r, pn1, wn1, std1, bias1, alpha1, h1bf);

    // ---- block 2 ----
    sq_cl_kernel<96><<<dim3(16 * 4096 / TPB), B, 0, stream>>>(h1bf, sbuf);
    win_sum_kernel<5, 2><<<dim3(16 * 4096 / TPB), B, 0, stream>>>(sbuf, pn2, 64, 64);
    wn_kernel<<<dim3(192), dim3(64), 0, stream>>>(w2, wn2, 2400);
    wt_reorder_kernel<<<dim3((192 * 2400 + TPB - 1) / TPB), B, 0, stream>>>(w2, w2bf, 192, 96, 25);
    conv2_mfma<<<dim3(16 * 2 * 8 * 4), B, 0, stream>>>(
        h1bf, w2bf, pn2, wn2, std2, bias2, alpha2, h2bf);

    // ---- block 3 ----
    sq_cl_kernel<192><<<dim3(16 * 1024 / TPB), B, 0, stream>>>(h2bf, sbuf);
    win_sum_kernel<3, 1><<<dim3(16 * 1024 / TPB), B, 0, stream>>>(sbuf, pn3, 32, 32);
    wn_kernel<<<dim3(384), dim3(64), 0, stream>>>(w3, wn3, 1728);
    wt_reorder_kernel<<<dim3((384 * 1728 + TPB - 1) / TPB), B, 0, stream>>>(w3, w3bf, 384, 192, 9);
    conv3_mfma<<<dim3(16 * 4 * 4 * 4), B, 0, stream>>>(
        h2bf, w3bf, pn3, wn3, std3, bias3, h3bf);

    // ---- fc ----
    fc_mfma<<<dim3(768), B, 0, stream>>>(h3bf, fc_w, fcp);
    fc_final<<<dim3(100), dim3(64), 0, stream>>>(fcp, fc_b, out);
}

// Round 4
// 269.145 us; speedup vs baseline: 5.0714x; 1.0025x over previous
//
#include <hip/hip_runtime.h>

#define TPB 256

typedef short bf16x8 __attribute__((ext_vector_type(8)));
typedef float f32x4 __attribute__((ext_vector_type(4)));

__device__ inline unsigned short f2bf(float f) {
    unsigned int u = __float_as_uint(f);
    unsigned int r = (u + 0x7fffu + ((u >> 16) & 1u)) >> 16;
    return (unsigned short)r;
}
__device__ inline float bf2f(unsigned short h) {
    return __uint_as_float(((unsigned int)h) << 16);
}

// ---------- small kernels ----------

__global__ void sq_sum_kernel(const float* __restrict__ src, float* __restrict__ dst,
                              int C, int HW) {
    int idx = blockIdx.x * TPB + threadIdx.x;
    int b = idx / HW, p = idx - b * HW;
    const float* s = src + (size_t)b * C * HW + p;
    float acc = 0.f;
    for (int c = 0; c < C; ++c) { float v = s[(size_t)c * HW]; acc += v * v; }
    dst[idx] = acc;
}

template<int C>
__global__ void sq_cl_kernel(const unsigned short* __restrict__ src, float* __restrict__ dst) {
    int idx = blockIdx.x * TPB + threadIdx.x;
    const unsigned short* s = src + (size_t)idx * C;
    float acc = 0.f;
    #pragma unroll
    for (int c = 0; c < C; c += 8) {
        bf16x8 v = *(const bf16x8*)&s[c];
        #pragma unroll
        for (int j = 0; j < 8; ++j) { float f = bf2f((unsigned short)v[j]); acc += f * f; }
    }
    dst[idx] = acc;
}

template<int K, int PAD>
__global__ void win_sum_kernel(const float* __restrict__ s, float* __restrict__ pn,
                               int H, int W) {
    int idx = blockIdx.x * TPB + threadIdx.x;
    int b = idx / (H * W); int rem = idx - b * H * W;
    int y = rem / W, x = rem - y * W;
    const float* sb = s + (size_t)b * H * W;
    float acc = 0.f;
    #pragma unroll
    for (int ki = 0; ki < K; ++ki) {
        int yy = y - PAD + ki;
        if (yy < 0 || yy >= H) continue;
        #pragma unroll
        for (int kj = 0; kj < K; ++kj) {
            int xx = x - PAD + kj;
            if (xx < 0 || xx >= W) continue;
            acc += sb[yy * W + xx];
        }
    }
    pn[idx] = acc;
}

__global__ void wn_kernel(const float* __restrict__ w, float* __restrict__ wn, int D) {
    int o = blockIdx.x;
    int lane = threadIdx.x;
    const float* row = w + (size_t)o * D;
    float acc = 0.f;
    for (int i = lane; i < D; i += 64) { float v = row[i]; acc += v * v; }
    #pragma unroll
    for (int off = 32; off >= 1; off >>= 1) acc += __shfl_down(acc, off);
    if (lane == 0) wn[o] = acc;
}

// reorder weights [O][C*KK] (c-major) -> bf16 [O][KK*C] (tap-major); for conv2/conv3
__global__ void wt_reorder_kernel(const float* __restrict__ w, unsigned short* __restrict__ wbf,
                                  int O, int C, int KK) {
    int idx = blockIdx.x * TPB + threadIdx.x;
    if (idx >= O * C * KK) return;
    int c = idx % C; int t = idx / C; int tap = t % KK; int o = t / KK;
    wbf[idx] = f2bf(w[((size_t)o * C + c) * KK + tap]);
}

// x [16,3,128,128] fp32 CF -> xbf [16][128][128][4] bf16 (c padded to 4 with 0)
__global__ void xbf_prep(const float* __restrict__ x, unsigned short* __restrict__ xbf) {
    int idx = blockIdx.x * TPB + threadIdx.x;  // 262144
    int b = idx >> 14, px = idx & 16383;
    const float* xb = x + (size_t)b * 3 * 16384 + px;
    ushort4 v;
    v.x = f2bf(xb[0]); v.y = f2bf(xb[16384]); v.z = f2bf(xb[32768]); v.w = 0;
    *(ushort4*)&xbf[(size_t)idx * 4] = v;
}

// w1 [96][75] (c*25 + ki*5+kj) -> w1r [96][136] bf16, d = tp*4+c,
// tp = ki*6+kj (rows padded to 6 taps, taps 30..33 zero), row padded 128->136
__global__ void wt1_reorder(const float* __restrict__ w1, unsigned short* __restrict__ w1r) {
    int idx = blockIdx.x * TPB + threadIdx.x;
    if (idx >= 96 * 136) return;
    int o = idx / 136, d = idx - o * 136;
    int tp = d >> 2, c = d & 3;
    float v = 0.f;
    if (tp < 30 && c < 3) {
        int ki = tp / 6, kj = tp - 6 * ki;
        if (kj < 5) v = w1[o * 75 + c * 25 + ki * 5 + kj];
    }
    w1r[idx] = f2bf(v);
}

// ---------- conv1: MFMA bf16, K=128 (32 taps x 4c) ----------
__launch_bounds__(256, 2)
__global__ void conv1_mfma(const unsigned short* __restrict__ xbf,
                           const unsigned short* __restrict__ w1r,
                           const float* __restrict__ pn, const float* __restrict__ wn,
                           const float* __restrict__ stdp, const float* __restrict__ biasp,
                           const float* __restrict__ alphap,
                           unsigned short* __restrict__ out) // [16][64][64][96] bf16 CL
{
    __shared__ unsigned short in_s[22 * 20 * 4];
    __shared__ unsigned short w_s[96 * 136];

    int bid = blockIdx.x;
    int tx = bid & 7; bid >>= 3;
    int ty = bid & 7; bid >>= 3;
    int b = bid;
    int x0 = tx * 16, y0 = ty * 16;
    int tid = threadIdx.x;
    int lane = tid & 63, wv = tid >> 6;
    int col = lane & 15, kg = lane >> 4;

    for (int idx = tid; idx < 21 * 20; idx += 256) {
        int py = idx / 20, px = idx - py * 20;
        int gy = y0 - 2 + py, gx = x0 - 2 + px;
        ushort4 v = make_ushort4(0, 0, 0, 0);
        if (gy >= 0 && gy < 128 && gx >= 0 && gx < 128)
            v = *(const ushort4*)&xbf[(((size_t)b * 128 + gy) * 128 + gx) * 4];
        *(ushort4*)&in_s[idx * 4] = v;
    }
    for (int idx = tid; idx < 1632; idx += 256)
        *(bf16x8*)&w_s[idx * 8] = *(const bf16x8*)&w1r[idx * 8];
    __syncthreads();

    f32x4 acc[6][4];
    #pragma unroll
    for (int mt = 0; mt < 6; ++mt)
        #pragma unroll
        for (int n = 0; n < 4; ++n) acc[mt][n] = (f32x4){0.f, 0.f, 0.f, 0.f};

    #pragma unroll
    for (int ks = 0; ks < 4; ++ks) {
        int tap0 = ks * 8 + kg * 2;
        int ki = tap0 / 6, kj = tap0 - 6 * ki;
        bf16x8 bfrag[4];
        #pragma unroll
        for (int n = 0; n < 4; ++n) {
            int row = wv * 4 + n + ki;
            int ix = col + kj;
            const unsigned short* p = &in_s[(row * 20 + ix) * 4];
            union { bf16x8 v; uint2 u[2]; } tmp;
            tmp.u[0] = *(const uint2*)p;
            tmp.u[1] = *(const uint2*)(p + 4);
            bfrag[n] = tmp.v;
        }
        bf16x8 afrag[6];
        #pragma unroll
        for (int mt = 0; mt < 6; ++mt)
            afrag[mt] = *(const bf16x8*)&w_s[(mt * 16 + col) * 136 + ks * 32 + kg * 8];
        #pragma unroll
        for (int mt = 0; mt < 6; ++mt)
            #pragma unroll
            for (int n = 0; n < 4; ++n)
                acc[mt][n] = __builtin_amdgcn_mfma_f32_16x16x32_bf16(
                    afrag[mt], bfrag[n], acc[mt][n], 0, 0, 0);
    }

    float stdv = stdp[0], biasv = biasp[0];
    float inv2s2 = 1.f / (2.f * stdv * stdv);
    float a00 = alphap[0], a01 = alphap[1], a10 = alphap[2], a11 = alphap[3];
    int dx = col & 1;
    float ax0 = dx ? a01 : a00;
    float ax1 = dx ? a11 : a10;
    float pnv[4];
    #pragma unroll
    for (int n = 0; n < 4; ++n)
        pnv[n] = pn[((size_t)b * 128 + (y0 + wv * 4 + n)) * 128 + x0 + col];

    #pragma unroll
    for (int mt = 0; mt < 6; ++mt) {
        #pragma unroll
        for (int p2 = 0; p2 < 2; ++p2) {
            unsigned short res[4];
            #pragma unroll
            for (int r = 0; r < 4; ++r) {
                int o = mt * 16 + kg * 4 + r;
                float wno = wn[o];
                float d20 = fmaxf(pnv[2 * p2] + wno - 2.f * acc[mt][2 * p2][r], 0.f);
                float d21 = fmaxf(pnv[2 * p2 + 1] + wno - 2.f * acc[mt][2 * p2 + 1][r], 0.f);
                float g0 = __expf(-d20 * inv2s2);
                float g1 = __expf(-d21 * inv2s2);
                g0 = (g0 >= biasv) ? g0 : 0.f;
                g1 = (g1 >= biasv) ? g1 : 0.f;
                float s = ax0 * g0 + ax1 * g1;
                s += __shfl_xor(s, 1);
                res[r] = f2bf(0.25f * s);
            }
            if (dx == 0) {
                int yo = ty * 8 + wv * 2 + p2, xo = tx * 8 + (col >> 1);
                *(ushort4*)&out[(((size_t)b * 64 + yo) * 64 + xo) * 96 + mt * 16 + kg * 4] =
                    make_ushort4(res[0], res[1], res[2], res[3]);
            }
        }
    }
}

// ---------- conv2: MFMA bf16, XOR-swizzled LDS ----------
// swizzle: ushort index ^= ((row_or_px & 7) << 3)  == byte bits 4-6 (banks spread 8-way)
__launch_bounds__(256, 2)
__global__ void conv2_mfma(const unsigned short* __restrict__ hin,
                           const unsigned short* __restrict__ wt,
                           const float* __restrict__ pn, const float* __restrict__ wn,
                           const float* __restrict__ stdp, const float* __restrict__ biasp,
                           const float* __restrict__ alphap,
                           unsigned short* __restrict__ hout) // [16][32][32][192] CL bf16
{
    __shared__ unsigned short in_s[12 * 20 * 96];
    __shared__ unsigned short w_s[96 * 96];

    int bid = blockIdx.x;
    int xt = bid & 3; bid >>= 2;
    int yt = bid & 7; bid >>= 3;
    int ot = bid & 1; int b = bid >> 1;
    int x0 = xt * 16, y0 = yt * 8, o0 = ot * 96;
    int tid = threadIdx.x;
    int lane = tid & 63, wid = tid >> 6;
    int wave_m = wid >> 1, wave_n = wid & 1;
    int col = lane & 15, kg = lane >> 4;

    #pragma unroll
    for (int it = 0; it < 12; ++it) {
        int idx = tid + it * 256;
        if (idx < 2880) {
            int px = idx / 12, ch = idx - px * 12;
            int iy = px / 20, ix = px - iy * 20;
            int gy = y0 - 2 + iy, gx = x0 - 2 + ix;
            bf16x8 v = {0, 0, 0, 0, 0, 0, 0, 0};
            if (gy >= 0 && gy < 64 && gx >= 0 && gx < 64)
                v = *(const bf16x8*)&hin[(((size_t)b * 64 + gy) * 64 + gx) * 96 + ch * 8];
            *(bf16x8*)&in_s[(idx * 8) ^ ((px & 7) << 3)] = v;
        }
    }
    #pragma unroll
    for (int it = 0; it < 5; ++it) {
        int idx = tid + it * 256;
        if (idx < 1152) {
            int row = idx / 12, ch = idx - row * 12;
            *(bf16x8*)&w_s[(idx * 8) ^ ((row & 7) << 3)] =
                *(const bf16x8*)&wt[(size_t)(o0 + row) * 2400 + ch * 8];
        }
    }
    __syncthreads();

    f32x4 acc[3][4];
    #pragma unroll
    for (int mt = 0; mt < 3; ++mt)
        #pragma unroll
        for (int nt = 0; nt < 4; ++nt) acc[mt][nt] = (f32x4){0.f, 0.f, 0.f, 0.f};

    for (int tap = 0; tap < 25; ++tap) {
        int ki = tap / 5, kj = tap - ki * 5;
        bf16x8 wreg[5];
        if (tap < 24) {
            #pragma unroll
            for (int it = 0; it < 5; ++it) {
                int idx = tid + it * 256;
                if (idx < 1152) {
                    int row = idx / 12, ch = idx - row * 12;
                    wreg[it] = *(const bf16x8*)&wt[(size_t)(o0 + row) * 2400 + (tap + 1) * 96 + ch * 8];
                }
            }
        }
        #pragma unroll
        for (int ks = 0; ks < 3; ++ks) {
            int c0 = ks * 32 + kg * 8;
            bf16x8 afrag[3], bfrag[4];
            #pragma unroll
            for (int mt = 0; mt < 3; ++mt) {
                int row = wave_m * 48 + mt * 16 + col;
                afrag[mt] = *(const bf16x8*)&w_s[(row * 96 + c0) ^ ((row & 7) << 3)];
            }
            #pragma unroll
            for (int nt = 0; nt < 4; ++nt) {
                int yy = 2 * nt + (col >> 3) + ki;
                int xx = wave_n * 8 + (col & 7) + kj;
                int px = yy * 20 + xx;
                bfrag[nt] = *(const bf16x8*)&in_s[(px * 96 + c0) ^ ((px & 7) << 3)];
            }
            #pragma unroll
            for (int mt = 0; mt < 3; ++mt)
                #pragma unroll
                for (int nt = 0; nt < 4; ++nt)
                    acc[mt][nt] = __builtin_amdgcn_mfma_f32_16x16x32_bf16(
                        afrag[mt], bfrag[nt], acc[mt][nt], 0, 0, 0);
        }
        __syncthreads();
        if (tap < 24) {
            #pragma unroll
            for (int it = 0; it < 5; ++it) {
                int idx = tid + it * 256;
                if (idx < 1152) {
                    int row = idx / 12;
                    *(bf16x8*)&w_s[(idx * 8) ^ ((row & 7) << 3)] = wreg[it];
                }
            }
        }
        __syncthreads();
    }

    float stdv = stdp[0], biasv = biasp[0];
    float inv2s2 = 1.f / (2.f * stdv * stdv);
    float a_own = alphap[(col >> 3) * 2 + (col & 1)];
    #pragma unroll
    for (int nt = 0; nt < 4; ++nt) {
        int y = y0 + 2 * nt + (col >> 3);
        int x = x0 + wave_n * 8 + (col & 7);
        float pnv = pn[((size_t)b * 64 + y) * 64 + x];
        int yo = (y0 >> 1) + nt;
        int xo = x >> 1;
        #pragma unroll
        for (int mt = 0; mt < 3; ++mt) {
            int ob = o0 + wave_m * 48 + mt * 16 + (kg << 2);
            unsigned short res[4];
            #pragma unroll
            for (int r = 0; r < 4; ++r) {
                float d2 = fmaxf(pnv + wn[ob + r] - 2.f * acc[mt][nt][r], 0.f);
                float g = __expf(-d2 * inv2s2);
                g = (g >= biasv) ? g : 0.f;
                g *= a_own;
                g += __shfl_xor(g, 1);
                g += __shfl_xor(g, 8);
                res[r] = f2bf(0.25f * g);
            }
            if (((col & 1) == 0) && ((col & 8) == 0)) {
                *(ushort4*)&hout[(((size_t)b * 32 + yo) * 32 + xo) * 192 + ob] =
                    make_ushort4(res[0], res[1], res[2], res[3]);
            }
        }
    }
}

// ---------- conv3: MFMA bf16 -> h3 bf16 CF flat ----------
__launch_bounds__(256, 2)
__global__ void conv3_mfma(const unsigned short* __restrict__ hin,
                           const unsigned short* __restrict__ wt,
                           const float* __restrict__ pn, const float* __restrict__ wn,
                           const float* __restrict__ stdp, const float* __restrict__ biasp,
                           unsigned short* __restrict__ hout) // [16][384*32*32] bf16 CF
{
    __shared__ unsigned short in_s[10 * 10 * 200];
    __shared__ unsigned short w_s[96 * 200];

    int bid = blockIdx.x;
    int xt = bid & 3; bid >>= 2;
    int yt = bid & 3; bid >>= 2;
    int ot = bid & 3; int b = bid >> 2;
    int x0 = xt * 8, y0 = yt * 8, o0 = ot * 96;
    int tid = threadIdx.x;
    int lane = tid & 63, wid = tid >> 6;
    int wave_m = wid >> 1, wave_n = wid & 1;
    int col = lane & 15, kg = lane >> 4;

    #pragma unroll
    for (int it = 0; it < 10; ++it) {
        int idx = tid + it * 256;
        if (idx < 2500) {
            int px = idx / 25, ch = idx - px * 25;
            int iy = px / 10, ix = px - iy * 10;
            int gy = y0 - 1 + iy, gx = x0 - 1 + ix;
            bf16x8 v = {0, 0, 0, 0, 0, 0, 0, 0};
            if (ch < 24 && gy >= 0 && gy < 32 && gx >= 0 && gx < 32)
                v = *(const bf16x8*)&hin[(((size_t)b * 32 + gy) * 32 + gx) * 192 + ch * 8];
            *(bf16x8*)&in_s[idx * 8] = v;
        }
    }
    #pragma unroll
    for (int it = 0; it < 10; ++it) {
        int idx = tid + it * 256;
        if (idx < 2400) {
            int row = idx / 25, ch = idx - row * 25;
            bf16x8 v = {0, 0, 0, 0, 0, 0, 0, 0};
            if (ch < 24)
                v = *(const bf16x8*)&wt[(size_t)(o0 + row) * 1728 + ch * 8];
            *(bf16x8*)&w_s[idx * 8] = v;
        }
    }
    __syncthreads();

    f32x4 acc[3][2];
    #pragma unroll
    for (int mt = 0; mt < 3; ++mt)
        #pragma unroll
        for (int nt = 0; nt < 2; ++nt) acc[mt][nt] = (f32x4){0.f, 0.f, 0.f, 0.f};

    for (int tap = 0; tap < 9; ++tap) {
        int ki = tap / 3, kj = tap - ki * 3;
        bf16x8 wreg[10];
        if (tap < 8) {
            #pragma unroll
            for (int it = 0; it < 10; ++it) {
                int idx = tid + it * 256;
                if (idx < 2400) {
                    int row = idx / 25, ch = idx - row * 25;
                    bf16x8 v = {0, 0, 0, 0, 0, 0, 0, 0};
                    if (ch < 24)
                        v = *(const bf16x8*)&wt[(size_t)(o0 + row) * 1728 + (tap + 1) * 192 + ch * 8];
                    wreg[it] = v;
                }
            }
        }
        #pragma unroll
        for (int ks = 0; ks < 6; ++ks) {
            int c0 = ks * 32 + kg * 8;
            bf16x8 afrag[3], bfrag[2];
            #pragma unroll
            for (int mt = 0; mt < 3; ++mt)
                afrag[mt] = *(const bf16x8*)&w_s[(wave_m * 48 + mt * 16 + col) * 200 + c0];
            #pragma unroll
            for (int nt = 0; nt < 2; ++nt) {
                int yy = wave_n * 4 + 2 * nt + (col >> 3) + ki;
                int xx = (col & 7) + kj;
                bfrag[nt] = *(const bf16x8*)&in_s[(yy * 10 + xx) * 200 + c0];
            }
            #pragma unroll
            for (int mt = 0; mt < 3; ++mt)
                #pragma unroll
                for (int nt = 0; nt < 2; ++nt)
                    acc[mt][nt] = __builtin_amdgcn_mfma_f32_16x16x32_bf16(
                        afrag[mt], bfrag[nt], acc[mt][nt], 0, 0, 0);
        }
        __syncthreads();
        if (tap < 8) {
            #pragma unroll
            for (int it = 0; it < 10; ++it) {
                int idx = tid + it * 256;
                if (idx < 2400) *(bf16x8*)&w_s[idx * 8] = wreg[it];
            }
        }
        __syncthreads();
    }

    float stdv = stdp[0], biasv = biasp[0];
    float inv2s2 = 1.f / (2.f * stdv * stdv);
    #pragma unroll
    for (int nt = 0; nt < 2; ++nt) {
        int y = y0 + wave_n * 4 + 2 * nt + (col >> 3);
        int x = x0 + (col & 7);
        float pnv = pn[((size_t)b * 32 + y) * 32 + x];
        #pragma unroll
        for (int mt = 0; mt < 3; ++mt) {
            int ob = o0 + wave_m * 48 + mt * 16 + (kg << 2);
            #pragma unroll
            for (int r = 0; r < 4; ++r) {
                float d2 = fmaxf(pnv + wn[ob + r] - 2.f * acc[mt][nt][r], 0.f);
                float g = __expf(-d2 * inv2s2);
                g = (g >= biasv) ? g : 0.f;
                hout[((size_t)b * 384 + ob + r) * 1024 + y * 32 + x] = f2bf(g);
            }
        }
    }
}

// ---------- FC: MFMA over K-chunks, prefetched fw loads ----------
__launch_bounds__(256, 4)
__global__ void fc_mfma(const unsigned short* __restrict__ h3bf,
                        const float* __restrict__ fw,
                        float* __restrict__ fcp) // [768][112][16]
{
    __shared__ unsigned short h3s[16 * 520];
    __shared__ unsigned short fws[16 * 520];
    __shared__ float red[4][16][16];
    const size_t KI = 393216;
    int ch = blockIdx.x;
    int i0 = ch * 512;
    int tid = threadIdx.x;
    int lane = tid & 63, wv = tid >> 6;
    int col = lane & 15, kg = lane >> 4;

    // stage h3 chunk (bf16)
    #pragma unroll
    for (int it = 0; it < 4; ++it) {
        int c = tid + it * 256;
        int b = c >> 6, off = (c & 63) * 8;
        *(bf16x8*)&h3s[b * 520 + off] = *(const bf16x8*)&h3bf[(size_t)b * KI + i0 + off];
    }

    // prologue: load jt=0 fw rows into regs
    float4 pre[8];
    #pragma unroll
    for (int it = 0; it < 8; ++it) {
        int c = tid + it * 256;
        int row = c >> 7, off4 = (c & 127) * 4;
        pre[it] = (row < 100) ? *(const float4*)&fw[(size_t)row * KI + i0 + off4]
                              : make_float4(0.f, 0.f, 0.f, 0.f);
    }

    for (int jt = 0; jt < 7; ++jt) {
        int j0 = jt * 16;
        // write current fw tile to LDS (bf16)
        #pragma unroll
        for (int it = 0; it < 8; ++it) {
            int c = tid + it * 256;
            int row = c >> 7, off4 = (c & 127) * 4;
            *(ushort4*)&fws[row * 520 + off4] =
                make_ushort4(f2bf(pre[it].x), f2bf(pre[it].y), f2bf(pre[it].z), f2bf(pre[it].w));
        }
        // issue next jt's loads (latency hides under MFMA+reduce)
        if (jt < 6) {
            #pragma unroll
            for (int it = 0; it < 8; ++it) {
                int c = tid + it * 256;
                int row = c >> 7, off4 = (c & 127) * 4;
                int j = j0 + 16 + row;
                pre[it] = (j < 100) ? *(const float4*)&fw[(size_t)j * KI + i0 + off4]
                                    : make_float4(0.f, 0.f, 0.f, 0.f);
            }
        }
        __syncthreads();
        f32x4 acc = (f32x4){0.f, 0.f, 0.f, 0.f};
        #pragma unroll
        for (int s = 0; s < 4; ++s) {
            int k = wv * 128 + s * 32 + kg * 8;
            bf16x8 af = *(const bf16x8*)&fws[col * 520 + k];
            bf16x8 bg = *(const bf16x8*)&h3s[col * 520 + k];
            acc = __builtin_amdgcn_mfma_f32_16x16x32_bf16(af, bg, acc, 0, 0, 0);
        }
        #pragma unroll
        for (int r = 0; r < 4; ++r) red[wv][kg * 4 + r][col] = acc[r];
        __syncthreads();
        int j = tid >> 4, bb = tid & 15;
        float s = red[0][j][bb] + red[1][j][bb] + red[2][j][bb] + red[3][j][bb];
        fcp[((size_t)ch * 112 + j0 + j) * 16 + bb] = s;
    }
}

// out[b][j] = fb[j] + sum_ch fcp[ch][j][b]; 100 blocks x 1 wave
__global__ void fc_final(const float* __restrict__ fcp, const float* __restrict__ fb,
                         float* __restrict__ outp) {
    int j = blockIdx.x;
    int lane = threadIdx.x;
    float acc[16];
    #pragma unroll
    for (int b = 0; b < 16; ++b) acc[b] = 0.f;
    for (int ch = lane; ch < 768; ch += 64) {
        const float* p = &fcp[((size_t)ch * 112 + j) * 16];
        #pragma unroll
        for (int b = 0; b < 16; ++b) acc[b] += p[b];
    }
    #pragma unroll
    for (int off = 32; off >= 1; off >>= 1)
        #pragma unroll
        for (int b = 0; b < 16; ++b) acc[b] += __shfl_down(acc[b], off);
    if (lane == 0) {
        float bj = fb[j];
        #pragma unroll
        for (int b = 0; b < 16; ++b) outp[b * 100 + j] = bj + acc[b];
    }
}

// ---------- launch ----------
extern "C" void kernel_launch(void* const* d_in, const int* in_sizes, int n_in,
                              void* d_out, int out_size, void* d_ws, size_t ws_size,
                              hipStream_t stream) {
    const float* x      = (const float*)d_in[0];
    const float* w1     = (const float*)d_in[1];
    const float* std1   = (const float*)d_in[2];
    const float* bias1  = (const float*)d_in[3];
    const float* alpha1 = (const float*)d_in[4];
    const float* w2     = (const float*)d_in[5];
    const float* std2   = (const float*)d_in[6];
    const float* bias2  = (const float*)d_in[7];
    const float* alpha2 = (const float*)d_in[8];
    const float* w3     = (const float*)d_in[9];
    const float* std3   = (const float*)d_in[10];
    const float* bias3  = (const float*)d_in[11];
    const float* fc_w   = (const float*)d_in[12];
    const float* fc_b   = (const float*)d_in[13];
    float* out = (float*)d_out;
    float* ws  = (float*)d_ws;

    // float region
    float* pn1   = ws;                  // 262144
    float* sbuf  = pn1 + 262144;        // 262144
    float* pn2   = sbuf + 262144;       // 65536
    float* pn3   = pn2 + 65536;         // 16384
    float* fcp   = pn3 + 16384;         // 1376256
    float* wn1   = fcp + 1376256;       // 96
    float* wn2   = wn1 + 96;            // 192
    float* wn3   = wn2 + 192;           // 384
    float* rest  = wn3 + 384 + 32;
    // ushort region
    unsigned short* h1bf = (unsigned short*)rest;  // 6291456
    unsigned short* h2bf = h1bf + 6291456;         // 3145728
    unsigned short* w2bf = h2bf + 3145728;         // 460800
    unsigned short* w3bf = w2bf + 460800;          // 663552
    unsigned short* h3bf = w3bf + 663552;          // 6291456
    unsigned short* xbf  = h3bf + 6291456;         // 1048576
    unsigned short* w1r  = xbf + 1048576;          // 13056

    dim3 B(TPB);

    // ---- block 1 ----
    xbf_prep<<<dim3(1024), B, 0, stream>>>(x, xbf);
    wt1_reorder<<<dim3(51), B, 0, stream>>>(w1, w1r);
    sq_sum_kernel<<<dim3(16 * 16384 / TPB), B, 0, stream>>>(x, sbuf, 3, 16384);
    win_sum_kernel<5, 2><<<dim3(16 * 16384 / TPB), B, 0, stream>>>(sbuf, pn1, 128, 128);
    wn_kernel<<<dim3(96), dim3(64), 0, stream>>>(w1, wn1, 75);
    conv1_mfma<<<dim3(1024), B, 0, stream>>>(xbf, w1r, pn1, wn1, std1, bias1, alpha1, h1bf);

    // ---- block 2 ----
    sq_cl_kernel<96><<<dim3(16 * 4096 / TPB), B, 0, stream>>>(h1bf, sbuf);
    win_sum_kernel<5, 2><<<dim3(16 * 4096 / TPB), B, 0, stream>>>(sbuf, pn2, 64, 64);
    wn_kernel<<<dim3(192), dim3(64), 0, stream>>>(w2, wn2, 2400);
    wt_reorder_kernel<<<dim3((192 * 2400 + TPB - 1) / TPB), B, 0, stream>>>(w2, w2bf, 192, 96, 25);
    conv2_mfma<<<dim3(16 * 2 * 8 * 4), B, 0, stream>>>(
        h1bf, w2bf, pn2, wn2, std2, bias2, alpha2, h2bf);

    // ---- block 3 ----
    sq_cl_kernel<192><<<dim3(16 * 1024 / TPB), B, 0, stream>>>(h2bf, sbuf);
    win_sum_kernel<3, 1><<<dim3(16 * 1024 / TPB), B, 0, stream>>>(sbuf, pn3, 32, 32);
    wn_kernel<<<dim3(384), dim3(64), 0, stream>>>(w3, wn3, 1728);
    wt_reorder_kernel<<<dim3((384 * 1728 + TPB - 1) / TPB), B, 0, stream>>>(w3, w3bf, 384, 192, 9);
    conv3_mfma<<<dim3(16 * 4 * 4 * 4), B, 0, stream>>>(
        h2bf, w3bf, pn3, wn3, std3, bias3, h3bf);

    // ---- fc ----
    fc_mfma<<<dim3(768), B, 0, stream>>>(h3bf, fc_w, fcp);
    fc_final<<<dim3(100), dim3(64), 0, stream>>>(fcp, fc_b, out);
}

// Round 5
// 229.310 us; speedup vs baseline: 5.9524x; 1.1737x over previous
//
#include <hip/hip_runtime.h>

#define TPB 256

typedef short bf16x8 __attribute__((ext_vector_type(8)));
typedef float f32x4 __attribute__((ext_vector_type(4)));

__device__ inline unsigned short f2bf(float f) {
    unsigned int u = __float_as_uint(f);
    unsigned int r = (u + 0x7fffu + ((u >> 16) & 1u)) >> 16;
    return (unsigned short)r;
}
__device__ inline float bf2f(unsigned short h) {
    return __uint_as_float(((unsigned int)h) << 16);
}

// async global->LDS 16B copy (dest: linear per-lane, src: per-lane arbitrary)
__device__ __forceinline__ void gl16(void* lds, const void* g) {
    __builtin_amdgcn_global_load_lds(
        (const __attribute__((address_space(1))) unsigned int*)g,
        (__attribute__((address_space(3))) unsigned int*)lds, 16, 0, 0);
}

// ---------- small kernels ----------

__global__ void zfill(unsigned short* z) { z[threadIdx.x] = 0; }

__global__ void sq_sum_kernel(const float* __restrict__ src, float* __restrict__ dst,
                              int C, int HW) {
    int idx = blockIdx.x * TPB + threadIdx.x;
    int b = idx / HW, p = idx - b * HW;
    const float* s = src + (size_t)b * C * HW + p;
    float acc = 0.f;
    for (int c = 0; c < C; ++c) { float v = s[(size_t)c * HW]; acc += v * v; }
    dst[idx] = acc;
}

template<int C>
__global__ void sq_cl_kernel(const unsigned short* __restrict__ src, float* __restrict__ dst) {
    int idx = blockIdx.x * TPB + threadIdx.x;
    const unsigned short* s = src + (size_t)idx * C;
    float acc = 0.f;
    #pragma unroll
    for (int c = 0; c < C; c += 8) {
        bf16x8 v = *(const bf16x8*)&s[c];
        #pragma unroll
        for (int j = 0; j < 8; ++j) { float f = bf2f((unsigned short)v[j]); acc += f * f; }
    }
    dst[idx] = acc;
}

template<int K, int PAD>
__global__ void win_sum_kernel(const float* __restrict__ s, float* __restrict__ pn,
                               int H, int W) {
    int idx = blockIdx.x * TPB + threadIdx.x;
    int b = idx / (H * W); int rem = idx - b * H * W;
    int y = rem / W, x = rem - y * W;
    const float* sb = s + (size_t)b * H * W;
    float acc = 0.f;
    #pragma unroll
    for (int ki = 0; ki < K; ++ki) {
        int yy = y - PAD + ki;
        if (yy < 0 || yy >= H) continue;
        #pragma unroll
        for (int kj = 0; kj < K; ++kj) {
            int xx = x - PAD + kj;
            if (xx < 0 || xx >= W) continue;
            acc += sb[yy * W + xx];
        }
    }
    pn[idx] = acc;
}

__global__ void wn_kernel(const float* __restrict__ w, float* __restrict__ wn, int D) {
    int o = blockIdx.x;
    int lane = threadIdx.x;
    const float* row = w + (size_t)o * D;
    float acc = 0.f;
    for (int i = lane; i < D; i += 64) { float v = row[i]; acc += v * v; }
    #pragma unroll
    for (int off = 32; off >= 1; off >>= 1) acc += __shfl_down(acc, off);
    if (lane == 0) wn[o] = acc;
}

// conv3 weights: [O][C*KK] (c-major) -> bf16 [O][KK*C] (tap-major)
__global__ void wt_reorder_kernel(const float* __restrict__ w, unsigned short* __restrict__ wbf,
                                  int O, int C, int KK) {
    int idx = blockIdx.x * TPB + threadIdx.x;
    if (idx >= O * C * KK) return;
    int c = idx % C; int t = idx / C; int tap = t % KK; int o = t / KK;
    wbf[idx] = f2bf(w[((size_t)o * C + c) * KK + tap]);
}

// conv2 weights: [192][96*25] -> bf16 [3 cg][26 taps(pad)][192 o][32 c]
__global__ void wt2_reorder(const float* __restrict__ w2, unsigned short* __restrict__ wr) {
    int idx = blockIdx.x * TPB + threadIdx.x;
    if (idx >= 3 * 26 * 192 * 32) return;
    int c = idx & 31; int r = idx >> 5;
    int o = r % 192; r /= 192;
    int tap = r % 26; int cg = r / 26;
    float v = 0.f;
    if (tap < 25) v = w2[((size_t)o * 96 + cg * 32 + c) * 25 + tap];
    wr[idx] = f2bf(v);
}

// x [16,3,128,128] fp32 CF -> xbf [16][128][128][4] bf16 (c padded to 4 with 0)
__global__ void xbf_prep(const float* __restrict__ x, unsigned short* __restrict__ xbf) {
    int idx = blockIdx.x * TPB + threadIdx.x;
    int b = idx >> 14, px = idx & 16383;
    const float* xb = x + (size_t)b * 3 * 16384 + px;
    ushort4 v;
    v.x = f2bf(xb[0]); v.y = f2bf(xb[16384]); v.z = f2bf(xb[32768]); v.w = 0;
    *(ushort4*)&xbf[(size_t)idx * 4] = v;
}

// w1 [96][75] -> w1r [96][136] bf16 (see round-2 comment)
__global__ void wt1_reorder(const float* __restrict__ w1, unsigned short* __restrict__ w1r) {
    int idx = blockIdx.x * TPB + threadIdx.x;
    if (idx >= 96 * 136) return;
    int o = idx / 136, d = idx - o * 136;
    int tp = d >> 2, c = d & 3;
    float v = 0.f;
    if (tp < 30 && c < 3) {
        int ki = tp / 6, kj = tp - 6 * ki;
        if (kj < 5) v = w1[o * 75 + c * 25 + ki * 5 + kj];
    }
    w1r[idx] = f2bf(v);
}

// ---------- conv1: MFMA bf16, K=128 (32 taps x 4c) ----------
__launch_bounds__(256, 2)
__global__ void conv1_mfma(const unsigned short* __restrict__ xbf,
                           const unsigned short* __restrict__ w1r,
                           const float* __restrict__ pn, const float* __restrict__ wn,
                           const float* __restrict__ stdp, const float* __restrict__ biasp,
                           const float* __restrict__ alphap,
                           unsigned short* __restrict__ out) // [16][64][64][96] bf16 CL
{
    __shared__ unsigned short in_s[22 * 20 * 4];
    __shared__ unsigned short w_s[96 * 136];

    int bid = blockIdx.x;
    int tx = bid & 7; bid >>= 3;
    int ty = bid & 7; bid >>= 3;
    int b = bid;
    int x0 = tx * 16, y0 = ty * 16;
    int tid = threadIdx.x;
    int lane = tid & 63, wv = tid >> 6;
    int col = lane & 15, kg = lane >> 4;

    for (int idx = tid; idx < 21 * 20; idx += 256) {
        int py = idx / 20, px = idx - py * 20;
        int gy = y0 - 2 + py, gx = x0 - 2 + px;
        ushort4 v = make_ushort4(0, 0, 0, 0);
        if (gy >= 0 && gy < 128 && gx >= 0 && gx < 128)
            v = *(const ushort4*)&xbf[(((size_t)b * 128 + gy) * 128 + gx) * 4];
        *(ushort4*)&in_s[idx * 4] = v;
    }
    for (int idx = tid; idx < 1632; idx += 256)
        *(bf16x8*)&w_s[idx * 8] = *(const bf16x8*)&w1r[idx * 8];
    __syncthreads();

    f32x4 acc[6][4];
    #pragma unroll
    for (int mt = 0; mt < 6; ++mt)
        #pragma unroll
        for (int n = 0; n < 4; ++n) acc[mt][n] = (f32x4){0.f, 0.f, 0.f, 0.f};

    #pragma unroll
    for (int ks = 0; ks < 4; ++ks) {
        int tap0 = ks * 8 + kg * 2;
        int ki = tap0 / 6, kj = tap0 - 6 * ki;
        bf16x8 bfrag[4];
        #pragma unroll
        for (int n = 0; n < 4; ++n) {
            int row = wv * 4 + n + ki;
            int ix = col + kj;
            const unsigned short* p = &in_s[(row * 20 + ix) * 4];
            union { bf16x8 v; uint2 u[2]; } tmp;
            tmp.u[0] = *(const uint2*)p;
            tmp.u[1] = *(const uint2*)(p + 4);
            bfrag[n] = tmp.v;
        }
        bf16x8 afrag[6];
        #pragma unroll
        for (int mt = 0; mt < 6; ++mt)
            afrag[mt] = *(const bf16x8*)&w_s[(mt * 16 + col) * 136 + ks * 32 + kg * 8];
        #pragma unroll
        for (int mt = 0; mt < 6; ++mt)
            #pragma unroll
            for (int n = 0; n < 4; ++n)
                acc[mt][n] = __builtin_amdgcn_mfma_f32_16x16x32_bf16(
                    afrag[mt], bfrag[n], acc[mt][n], 0, 0, 0);
    }

    float stdv = stdp[0], biasv = biasp[0];
    float inv2s2 = 1.f / (2.f * stdv * stdv);
    float a00 = alphap[0], a01 = alphap[1], a10 = alphap[2], a11 = alphap[3];
    int dx = col & 1;
    float ax0 = dx ? a01 : a00;
    float ax1 = dx ? a11 : a10;
    float pnv[4];
    #pragma unroll
    for (int n = 0; n < 4; ++n)
        pnv[n] = pn[((size_t)b * 128 + (y0 + wv * 4 + n)) * 128 + x0 + col];

    #pragma unroll
    for (int mt = 0; mt < 6; ++mt) {
        #pragma unroll
        for (int p2 = 0; p2 < 2; ++p2) {
            unsigned short res[4];
            #pragma unroll
            for (int r = 0; r < 4; ++r) {
                int o = mt * 16 + kg * 4 + r;
                float wno = wn[o];
                float d20 = fmaxf(pnv[2 * p2] + wno - 2.f * acc[mt][2 * p2][r], 0.f);
                float d21 = fmaxf(pnv[2 * p2 + 1] + wno - 2.f * acc[mt][2 * p2 + 1][r], 0.f);
                float g0 = __expf(-d20 * inv2s2);
                float g1 = __expf(-d21 * inv2s2);
                g0 = (g0 >= biasv) ? g0 : 0.f;
                g1 = (g1 >= biasv) ? g1 : 0.f;
                float s = ax0 * g0 + ax1 * g1;
                s += __shfl_xor(s, 1);
                res[r] = f2bf(0.25f * s);
            }
            if (dx == 0) {
                int yo = ty * 8 + wv * 2 + p2, xo = tx * 8 + (col >> 1);
                *(ushort4*)&out[(((size_t)b * 64 + yo) * 64 + xo) * 96 + mt * 16 + kg * 4] =
                    make_ushort4(res[0], res[1], res[2], res[3]);
            }
        }
    }
}

// ---------- conv2: MFMA bf16, c-group 32, tap-pair dbuf, async LDS staging ----------
// Block 96o x 128px (16x8), 4 waves (2m x 2n). LDS ~39 KB -> 4 blocks/CU.
__launch_bounds__(256, 4)
__global__ void conv2_mfma(const unsigned short* __restrict__ hin,  // [16][64][64][96] CL
                           const unsigned short* __restrict__ wt2,  // [3][26][192][32] bf16
                           const float* __restrict__ pn, const float* __restrict__ wn,
                           const float* __restrict__ stdp, const float* __restrict__ biasp,
                           const float* __restrict__ alphap,
                           const unsigned short* __restrict__ zerob,
                           unsigned short* __restrict__ hout) // [16][32][32][192] CL bf16
{
    __shared__ unsigned short in_s[240 * 32];      // [py*20+px][32c]  15360 B
    __shared__ unsigned short w_s[2][2 * 96 * 32]; // [buf][tap][row][32c]  24576 B

    int bid = blockIdx.x;
    int xt = bid & 3; bid >>= 2;
    int yt = bid & 7; bid >>= 3;
    int ot = bid & 1; int b = bid >> 1;
    int x0 = xt * 16, y0 = yt * 8, o0 = ot * 96;
    int tid = threadIdx.x;
    int lane = tid & 63, wid = tid >> 6;
    int wave_m = wid >> 1, wave_n = wid & 1;
    int col = lane & 15, kg = lane >> 4;

    f32x4 acc[3][4];
    #pragma unroll
    for (int mt = 0; mt < 3; ++mt)
        #pragma unroll
        for (int nt = 0; nt < 4; ++nt) acc[mt][nt] = (f32x4){0.f, 0.f, 0.f, 0.f};

    for (int cg = 0; cg < 3; ++cg) {
        // stage input c-slice [12][20][32] (async; halo lanes read zero scratch)
        #pragma unroll
        for (int i = 0; i < 4; ++i) {
            int chunk = tid + i * 256;
            if (chunk < 960) {
                int px = chunk >> 2, c16 = chunk & 3;
                int iy = px / 20, ix = px - iy * 20;
                int gy = y0 - 2 + iy, gx = x0 - 2 + ix;
                const void* src = (gy >= 0 && gy < 64 && gx >= 0 && gx < 64)
                    ? (const void*)&hin[(((size_t)b * 64 + gy) * 64 + gx) * 96 + cg * 32 + c16 * 8]
                    : (const void*)zerob;
                gl16(&in_s[chunk * 8], src);
            }
        }
        // stage weight pair 0 -> buf0 (768 chunks = 3*256 exactly)
        #pragma unroll
        for (int i = 0; i < 3; ++i) {
            int chunk = tid + i * 256;
            int tp = chunk / 384, rem = chunk - tp * 384;
            gl16(&w_s[0][tp * 3072 + rem * 8],
                 &wt2[(((size_t)cg * 26 + tp) * 192 + o0) * 32 + rem * 8]);
        }
        __syncthreads();

        for (int pr = 0; pr < 13; ++pr) {
            int cur = pr & 1;
            if (pr < 12) {
                int nxt = cur ^ 1;
                #pragma unroll
                for (int i = 0; i < 3; ++i) {
                    int chunk = tid + i * 256;
                    int tp = chunk / 384, rem = chunk - tp * 384;
                    gl16(&w_s[nxt][tp * 3072 + rem * 8],
                         &wt2[(((size_t)cg * 26 + (pr + 1) * 2 + tp) * 192 + o0) * 32 + rem * 8]);
                }
            }
            #pragma unroll
            for (int t2 = 0; t2 < 2; ++t2) {
                int tap = pr * 2 + t2;
                int ki = tap / 5, kj = tap - 5 * ki;
                if (tap >= 25) { ki = 0; kj = 0; }   // dummy tap: zero weights
                bf16x8 afrag[3], bfrag[4];
                #pragma unroll
                for (int mt = 0; mt < 3; ++mt)
                    afrag[mt] = *(const bf16x8*)
                        &w_s[cur][(t2 * 96 + wave_m * 48 + mt * 16 + col) * 32 + kg * 8];
                #pragma unroll
                for (int nt = 0; nt < 4; ++nt) {
                    int yy = 2 * nt + (col >> 3) + ki;
                    int xx = wave_n * 8 + (col & 7) + kj;
                    bfrag[nt] = *(const bf16x8*)&in_s[(yy * 20 + xx) * 32 + kg * 8];
                }
                #pragma unroll
                for (int mt = 0; mt < 3; ++mt)
                    #pragma unroll
                    for (int nt = 0; nt < 4; ++nt)
                        acc[mt][nt] = __builtin_amdgcn_mfma_f32_16x16x32_bf16(
                            afrag[mt], bfrag[nt], acc[mt][nt], 0, 0, 0);
            }
            __syncthreads();
        }
    }

    // epilogue: d2 -> gauss -> crelu -> alpha-weighted 2x2 mean pool -> bf16 CL
    float stdv = stdp[0], biasv = biasp[0];
    float inv2s2 = 1.f / (2.f * stdv * stdv);
    float a_own = alphap[(col >> 3) * 2 + (col & 1)];
    #pragma unroll
    for (int nt = 0; nt < 4; ++nt) {
        int y = y0 + 2 * nt + (col >> 3);
        int x = x0 + wave_n * 8 + (col & 7);
        float pnv = pn[((size_t)b * 64 + y) * 64 + x];
        int yo = (y0 >> 1) + nt;
        int xo = x >> 1;
        #pragma unroll
        for (int mt = 0; mt < 3; ++mt) {
            int ob = o0 + wave_m * 48 + mt * 16 + (kg << 2);
            unsigned short res[4];
            #pragma unroll
            for (int r = 0; r < 4; ++r) {
                float d2 = fmaxf(pnv + wn[ob + r] - 2.f * acc[mt][nt][r], 0.f);
                float g = __expf(-d2 * inv2s2);
                g = (g >= biasv) ? g : 0.f;
                g *= a_own;
                g += __shfl_xor(g, 1);
                g += __shfl_xor(g, 8);
                res[r] = f2bf(0.25f * g);
            }
            if (((col & 1) == 0) && ((col & 8) == 0)) {
                *(ushort4*)&hout[(((size_t)b * 32 + yo) * 32 + xo) * 192 + ob] =
                    make_ushort4(res[0], res[1], res[2], res[3]);
            }
        }
    }
}

// ---------- conv3: MFMA bf16 -> h3 bf16 CF flat (unchanged) ----------
__launch_bounds__(256, 2)
__global__ void conv3_mfma(const unsigned short* __restrict__ hin,
                           const unsigned short* __restrict__ wt,
                           const float* __restrict__ pn, const float* __restrict__ wn,
                           const float* __restrict__ stdp, const float* __restrict__ biasp,
                           unsigned short* __restrict__ hout) // [16][384*32*32] bf16 CF
{
    __shared__ unsigned short in_s[10 * 10 * 200];
    __shared__ unsigned short w_s[96 * 200];

    int bid = blockIdx.x;
    int xt = bid & 3; bid >>= 2;
    int yt = bid & 3; bid >>= 2;
    int ot = bid & 3; int b = bid >> 2;
    int x0 = xt * 8, y0 = yt * 8, o0 = ot * 96;
    int tid = threadIdx.x;
    int lane = tid & 63, wid = tid >> 6;
    int wave_m = wid >> 1, wave_n = wid & 1;
    int col = lane & 15, kg = lane >> 4;

    #pragma unroll
    for (int it = 0; it < 10; ++it) {
        int idx = tid + it * 256;
        if (idx < 2500) {
            int px = idx / 25, ch = idx - px * 25;
            int iy = px / 10, ix = px - iy * 10;
            int gy = y0 - 1 + iy, gx = x0 - 1 + ix;
            bf16x8 v = {0, 0, 0, 0, 0, 0, 0, 0};
            if (ch < 24 && gy >= 0 && gy < 32 && gx >= 0 && gx < 32)
                v = *(const bf16x8*)&hin[(((size_t)b * 32 + gy) * 32 + gx) * 192 + ch * 8];
            *(bf16x8*)&in_s[idx * 8] = v;
        }
    }
    #pragma unroll
    for (int it = 0; it < 10; ++it) {
        int idx = tid + it * 256;
        if (idx < 2400) {
            int row = idx / 25, ch = idx - row * 25;
            bf16x8 v = {0, 0, 0, 0, 0, 0, 0, 0};
            if (ch < 24)
                v = *(const bf16x8*)&wt[(size_t)(o0 + row) * 1728 + ch * 8];
            *(bf16x8*)&w_s[idx * 8] = v;
        }
    }
    __syncthreads();

    f32x4 acc[3][2];
    #pragma unroll
    for (int mt = 0; mt < 3; ++mt)
        #pragma unroll
        for (int nt = 0; nt < 2; ++nt) acc[mt][nt] = (f32x4){0.f, 0.f, 0.f, 0.f};

    for (int tap = 0; tap < 9; ++tap) {
        int ki = tap / 3, kj = tap - ki * 3;
        bf16x8 wreg[10];
        if (tap < 8) {
            #pragma unroll
            for (int it = 0; it < 10; ++it) {
                int idx = tid + it * 256;
                if (idx < 2400) {
                    int row = idx / 25, ch = idx - row * 25;
                    bf16x8 v = {0, 0, 0, 0, 0, 0, 0, 0};
                    if (ch < 24)
                        v = *(const bf16x8*)&wt[(size_t)(o0 + row) * 1728 + (tap + 1) * 192 + ch * 8];
                    wreg[it] = v;
                }
            }
        }
        #pragma unroll
        for (int ks = 0; ks < 6; ++ks) {
            int c0 = ks * 32 + kg * 8;
            bf16x8 afrag[3], bfrag[2];
            #pragma unroll
            for (int mt = 0; mt < 3; ++mt)
                afrag[mt] = *(const bf16x8*)&w_s[(wave_m * 48 + mt * 16 + col) * 200 + c0];
            #pragma unroll
            for (int nt = 0; nt < 2; ++nt) {
                int yy = wave_n * 4 + 2 * nt + (col >> 3) + ki;
                int xx = (col & 7) + kj;
                bfrag[nt] = *(const bf16x8*)&in_s[(yy * 10 + xx) * 200 + c0];
            }
            #pragma unroll
            for (int mt = 0; mt < 3; ++mt)
                #pragma unroll
                for (int nt = 0; nt < 2; ++nt)
                    acc[mt][nt] = __builtin_amdgcn_mfma_f32_16x16x32_bf16(
                        afrag[mt], bfrag[nt], acc[mt][nt], 0, 0, 0);
        }
        __syncthreads();
        if (tap < 8) {
            #pragma unroll
            for (int it = 0; it < 10; ++it) {
                int idx = tid + it * 256;
                if (idx < 2400) *(bf16x8*)&w_s[idx * 8] = wreg[it];
            }
        }
        __syncthreads();
    }

    float stdv = stdp[0], biasv = biasp[0];
    float inv2s2 = 1.f / (2.f * stdv * stdv);
    #pragma unroll
    for (int nt = 0; nt < 2; ++nt) {
        int y = y0 + wave_n * 4 + 2 * nt + (col >> 3);
        int x = x0 + (col & 7);
        float pnv = pn[((size_t)b * 32 + y) * 32 + x];
        #pragma unroll
        for (int mt = 0; mt < 3; ++mt) {
            int ob = o0 + wave_m * 48 + mt * 16 + (kg << 2);
            #pragma unroll
            for (int r = 0; r < 4; ++r) {
                float d2 = fmaxf(pnv + wn[ob + r] - 2.f * acc[mt][nt][r], 0.f);
                float g = __expf(-d2 * inv2s2);
                g = (g >= biasv) ? g : 0.f;
                hout[((size_t)b * 384 + ob + r) * 1024 + y * 32 + x] = f2bf(g);
            }
        }
    }
}

// ---------- FC: MFMA over K-chunks, prefetched fw loads ----------
__launch_bounds__(256, 4)
__global__ void fc_mfma(const unsigned short* __restrict__ h3bf,
                        const float* __restrict__ fw,
                        float* __restrict__ fcp) // [768][112][16]
{
    __shared__ unsigned short h3s[16 * 520];
    __shared__ unsigned short fws[16 * 520];
    __shared__ float red[4][16][16];
    const size_t KI = 393216;
    int ch = blockIdx.x;
    int i0 = ch * 512;
    int tid = threadIdx.x;
    int lane = tid & 63, wv = tid >> 6;
    int col = lane & 15, kg = lane >> 4;

    #pragma unroll
    for (int it = 0; it < 4; ++it) {
        int c = tid + it * 256;
        int b = c >> 6, off = (c & 63) * 8;
        *(bf16x8*)&h3s[b * 520 + off] = *(const bf16x8*)&h3bf[(size_t)b * KI + i0 + off];
    }

    float4 pre[8];
    #pragma unroll
    for (int it = 0; it < 8; ++it) {
        int c = tid + it * 256;
        int row = c >> 7, off4 = (c & 127) * 4;
        pre[it] = (row < 100) ? *(const float4*)&fw[(size_t)row * KI + i0 + off4]
                              : make_float4(0.f, 0.f, 0.f, 0.f);
    }

    for (int jt = 0; jt < 7; ++jt) {
        int j0 = jt * 16;
        #pragma unroll
        for (int it = 0; it < 8; ++it) {
            int c = tid + it * 256;
            int row = c >> 7, off4 = (c & 127) * 4;
            *(ushort4*)&fws[row * 520 + off4] =
                make_ushort4(f2bf(pre[it].x), f2bf(pre[it].y), f2bf(pre[it].z), f2bf(pre[it].w));
        }
        if (jt < 6) {
            #pragma unroll
            for (int it = 0; it < 8; ++it) {
                int c = tid + it * 256;
                int row = c >> 7, off4 = (c & 127) * 4;
                int j = j0 + 16 + row;
                pre[it] = (j < 100) ? *(const float4*)&fw[(size_t)j * KI + i0 + off4]
                                    : make_float4(0.f, 0.f, 0.f, 0.f);
            }
        }
        __syncthreads();
        f32x4 acc = (f32x4){0.f, 0.f, 0.f, 0.f};
        #pragma unroll
        for (int s = 0; s < 4; ++s) {
            int k = wv * 128 + s * 32 + kg * 8;
            bf16x8 af = *(const bf16x8*)&fws[col * 520 + k];
            bf16x8 bg = *(const bf16x8*)&h3s[col * 520 + k];
            acc = __builtin_amdgcn_mfma_f32_16x16x32_bf16(af, bg, acc, 0, 0, 0);
        }
        #pragma unroll
        for (int r = 0; r < 4; ++r) red[wv][kg * 4 + r][col] = acc[r];
        __syncthreads();
        int j = tid >> 4, bb = tid & 15;
        float s = red[0][j][bb] + red[1][j][bb] + red[2][j][bb] + red[3][j][bb];
        fcp[((size_t)ch * 112 + j0 + j) * 16 + bb] = s;
    }
}

__global__ void fc_final(const float* __restrict__ fcp, const float* __restrict__ fb,
                         float* __restrict__ outp) {
    int j = blockIdx.x;
    int lane = threadIdx.x;
    float acc[16];
    #pragma unroll
    for (int b = 0; b < 16; ++b) acc[b] = 0.f;
    for (int ch = lane; ch < 768; ch += 64) {
        const float* p = &fcp[((size_t)ch * 112 + j) * 16];
        #pragma unroll
        for (int b = 0; b < 16; ++b) acc[b] += p[b];
    }
    #pragma unroll
    for (int off = 32; off >= 1; off >>= 1)
        #pragma unroll
        for (int b = 0; b < 16; ++b) acc[b] += __shfl_down(acc[b], off);
    if (lane == 0) {
        float bj = fb[j];
        #pragma unroll
        for (int b = 0; b < 16; ++b) outp[b * 100 + j] = bj + acc[b];
    }
}

// ---------- launch ----------
extern "C" void kernel_launch(void* const* d_in, const int* in_sizes, int n_in,
                              void* d_out, int out_size, void* d_ws, size_t ws_size,
                              hipStream_t stream) {
    const float* x      = (const float*)d_in[0];
    const float* w1     = (const float*)d_in[1];
    const float* std1   = (const float*)d_in[2];
    const float* bias1  = (const float*)d_in[3];
    const float* alpha1 = (const float*)d_in[4];
    const float* w2     = (const float*)d_in[5];
    const float* std2   = (const float*)d_in[6];
    const float* bias2  = (const float*)d_in[7];
    const float* alpha2 = (const float*)d_in[8];
    const float* w3     = (const float*)d_in[9];
    const float* std3   = (const float*)d_in[10];
    const float* bias3  = (const float*)d_in[11];
    const float* fc_w   = (const float*)d_in[12];
    const float* fc_b   = (const float*)d_in[13];
    float* out = (float*)d_out;
    float* ws  = (float*)d_ws;

    // float region
    float* pn1   = ws;                  // 262144
    float* sbuf  = pn1 + 262144;        // 262144
    float* pn2   = sbuf + 262144;       // 65536
    float* pn3   = pn2 + 65536;         // 16384
    float* fcp   = pn3 + 16384;         // 1376256
    float* wn1   = fcp + 1376256;       // 96
    float* wn2   = wn1 + 96;            // 192
    float* wn3   = wn2 + 192;           // 384
    float* rest  = wn3 + 384 + 32;      // 16B-aligned boundary
    // ushort region (all sizes multiples of 8 -> 16B alignment preserved)
    unsigned short* h1bf = (unsigned short*)rest;  // 6291456
    unsigned short* h2bf = h1bf + 6291456;         // 3145728
    unsigned short* w3bf = h2bf + 3145728;         // 663552
    unsigned short* h3bf = w3bf + 663552;          // 6291456
    unsigned short* xbf  = h3bf + 6291456;         // 1048576
    unsigned short* w1r  = xbf + 1048576;          // 13056
    unsigned short* w2r2 = w1r + 13056;            // 479232 = 3*26*192*32
    unsigned short* zerob = w2r2 + 479232;         // 64

    dim3 B(TPB);

    zfill<<<dim3(1), dim3(64), 0, stream>>>(zerob);

    // ---- block 1 ----
    xbf_prep<<<dim3(1024), B, 0, stream>>>(x, xbf);
    wt1_reorder<<<dim3(51), B, 0, stream>>>(w1, w1r);
    sq_sum_kernel<<<dim3(16 * 16384 / TPB), B, 0, stream>>>(x, sbuf, 3, 16384);
    win_sum_kernel<5, 2><<<dim3(16 * 16384 / TPB), B, 0, stream>>>(sbuf, pn1, 128, 128);
    wn_kernel<<<dim3(96), dim3(64), 0, stream>>>(w1, wn1, 75);
    conv1_mfma<<<dim3(1024), B, 0, stream>>>(xbf, w1r, pn1, wn1, std1, bias1, alpha1, h1bf);

    // ---- block 2 ----
    sq_cl_kernel<96><<<dim3(16 * 4096 / TPB), B, 0, stream>>>(h1bf, sbuf);
    win_sum_kernel<5, 2><<<dim3(16 * 4096 / TPB), B, 0, stream>>>(sbuf, pn2, 64, 64);
    wn_kernel<<<dim3(192), dim3(64), 0, stream>>>(w2, wn2, 2400);
    wt2_reorder<<<dim3((3 * 26 * 192 * 32 + TPB - 1) / TPB), B, 0, stream>>>(w2, w2r2);
    conv2_mfma<<<dim3(16 * 2 * 8 * 4), B, 0, stream>>>(
        h1bf, w2r2, pn2, wn2, std2, bias2, alpha2, zerob, h2bf);

    // ---- block 3 ----
    sq_cl_kernel<192><<<dim3(16 * 1024 / TPB), B, 0, stream>>>(h2bf, sbuf);
    win_sum_kernel<3, 1><<<dim3(16 * 1024 / TPB), B, 0, stream>>>(sbuf, pn3, 32, 32);
    wn_kernel<<<dim3(384), dim3(64), 0, stream>>>(w3, wn3, 1728);
    wt_reorder_kernel<<<dim3((384 * 1728 + TPB - 1) / TPB), B, 0, stream>>>(w3, w3bf, 384, 192, 9);
    conv3_mfma<<<dim3(16 * 4 * 4 * 4), B, 0, stream>>>(
        h2bf, w3bf, pn3, wn3, std3, bias3, h3bf);

    // ---- fc ----
    fc_mfma<<<dim3(768), B, 0, stream>>>(h3bf, fc_w, fcp);
    fc_final<<<dim3(100), dim3(64), 0, stream>>>(fcp, fc_b, out);
}

// Round 6
// 188.780 us; speedup vs baseline: 7.2303x; 1.2147x over previous
//
#include <hip/hip_runtime.h>

#define TPB 256

typedef short bf16x8 __attribute__((ext_vector_type(8)));
typedef float f32x4 __attribute__((ext_vector_type(4)));

__device__ inline unsigned short f2bf(float f) {
    unsigned int u = __float_as_uint(f);
    unsigned int r = (u + 0x7fffu + ((u >> 16) & 1u)) >> 16;
    return (unsigned short)r;
}
__device__ inline float bf2f(unsigned short h) {
    return __uint_as_float(((unsigned int)h) << 16);
}

// async global->LDS 16B copy (dest: linear wave-order, src: per-lane)
__device__ __forceinline__ void gl16(void* lds, const void* g) {
    __builtin_amdgcn_global_load_lds(
        (const __attribute__((address_space(1))) unsigned int*)g,
        (__attribute__((address_space(3))) unsigned int*)lds, 16, 0, 0);
}

// ---------- small kernels ----------

// x [16,3,128,128] fp32 CF -> xbf [16][128][128][4] bf16 + sq plane (fp32)
__global__ void xbf_prep_sq(const float* __restrict__ x, unsigned short* __restrict__ xbf,
                            float* __restrict__ sq) {
    int idx = blockIdx.x * TPB + threadIdx.x;
    int b = idx >> 14, px = idx & 16383;
    const float* xb = x + (size_t)b * 3 * 16384 + px;
    float v0 = xb[0], v1 = xb[16384], v2 = xb[32768];
    ushort4 v;
    v.x = f2bf(v0); v.y = f2bf(v1); v.z = f2bf(v2); v.w = 0;
    *(ushort4*)&xbf[(size_t)idx * 4] = v;
    sq[idx] = v0 * v0 + v1 * v1 + v2 * v2;
}

template<int C>
__global__ void sq_cl_kernel(const unsigned short* __restrict__ src, float* __restrict__ dst) {
    int idx = blockIdx.x * TPB + threadIdx.x;
    const unsigned short* s = src + (size_t)idx * C;
    float acc = 0.f;
    #pragma unroll
    for (int c = 0; c < C; c += 8) {
        bf16x8 v = *(const bf16x8*)&s[c];
        #pragma unroll
        for (int j = 0; j < 8; ++j) { float f = bf2f((unsigned short)v[j]); acc += f * f; }
    }
    dst[idx] = acc;
}

template<int K, int PAD>
__global__ void win_sum_kernel(const float* __restrict__ s, float* __restrict__ pn,
                               int H, int W) {
    int idx = blockIdx.x * TPB + threadIdx.x;
    int b = idx / (H * W); int rem = idx - b * H * W;
    int y = rem / W, x = rem - y * W;
    const float* sb = s + (size_t)b * H * W;
    float acc = 0.f;
    #pragma unroll
    for (int ki = 0; ki < K; ++ki) {
        int yy = y - PAD + ki;
        if (yy < 0 || yy >= H) continue;
        #pragma unroll
        for (int kj = 0; kj < K; ++kj) {
            int xx = x - PAD + kj;
            if (xx < 0 || xx >= W) continue;
            acc += sb[yy * W + xx];
        }
    }
    pn[idx] = acc;
}

// all three layers' weight row norms; 672 blocks x 64 lanes
__global__ void wn_all(const float* __restrict__ w1, const float* __restrict__ w2,
                       const float* __restrict__ w3,
                       float* __restrict__ wn1, float* __restrict__ wn2,
                       float* __restrict__ wn3) {
    int o = blockIdx.x;
    const float* row; float* dst; int D;
    if (o < 96)       { row = w1 + (size_t)o * 75;           D = 75;   dst = wn1 + o; }
    else if (o < 288) { int r = o - 96;  row = w2 + (size_t)r * 2400; D = 2400; dst = wn2 + r; }
    else              { int r = o - 288; row = w3 + (size_t)r * 1728; D = 1728; dst = wn3 + r; }
    int lane = threadIdx.x;
    float acc = 0.f;
    for (int i = lane; i < D; i += 64) { float v = row[i]; acc += v * v; }
    #pragma unroll
    for (int off = 32; off >= 1; off >>= 1) acc += __shfl_down(acc, off);
    if (lane == 0) *dst = acc;
}

// all weight reorders + zerob in one kernel
// w1r [96][136]; w2r [3][26][192][32]; w3r [6][10][192][32]; zerob [64]
__global__ void wt_all(const float* __restrict__ w1, const float* __restrict__ w2,
                       const float* __restrict__ w3,
                       unsigned short* __restrict__ w1r, unsigned short* __restrict__ w2r,
                       unsigned short* __restrict__ w3r, unsigned short* __restrict__ zerob) {
    int idx = blockIdx.x * TPB + threadIdx.x;
    if (idx < 13056) {
        int o = idx / 136, d = idx - o * 136;
        int tp = d >> 2, c = d & 3;
        float v = 0.f;
        if (tp < 30 && c < 3) {
            int ki = tp / 6, kj = tp - 6 * ki;
            if (kj < 5) v = w1[o * 75 + c * 25 + ki * 5 + kj];
        }
        w1r[idx] = f2bf(v);
    } else if (idx < 13056 + 479232) {
        int i = idx - 13056;
        int c = i & 31; int r = i >> 5;
        int o = r % 192; r /= 192;
        int tap = r % 26; int cg = r / 26;
        float v = 0.f;
        if (tap < 25) v = w2[((size_t)o * 96 + cg * 32 + c) * 25 + tap];
        w2r[i] = f2bf(v);
    } else if (idx < 13056 + 479232 + 368640) {
        int i = idx - 13056 - 479232;
        int c = i & 31; int r = i >> 5;
        int o = r % 192; r /= 192;
        int tap = r % 10; int cg = r / 10;
        float v = 0.f;
        if (tap < 9) v = w3[((size_t)o * 192 + cg * 32 + c) * 9 + tap];
        w3r[i] = f2bf(v);
    } else if (idx < 13056 + 479232 + 368640 + 64) {
        zerob[idx - 13056 - 479232 - 368640] = 0;
    }
}

// ---------- conv1: MFMA bf16, K=128 (32 taps x 4c); epilogue also emits sq plane ----------
__launch_bounds__(256, 2)
__global__ void conv1_mfma(const unsigned short* __restrict__ xbf,
                           const unsigned short* __restrict__ w1r,
                           const float* __restrict__ pn, const float* __restrict__ wn,
                           const float* __restrict__ stdp, const float* __restrict__ biasp,
                           const float* __restrict__ alphap,
                           unsigned short* __restrict__ out,  // [16][64][64][96] bf16 CL
                           float* __restrict__ sqout)         // [16][64][64] fp32
{
    __shared__ unsigned short in_s[22 * 20 * 4];
    __shared__ unsigned short w_s[96 * 136];

    int bid = blockIdx.x;
    int tx = bid & 7; bid >>= 3;
    int ty = bid & 7; bid >>= 3;
    int b = bid;
    int x0 = tx * 16, y0 = ty * 16;
    int tid = threadIdx.x;
    int lane = tid & 63, wv = tid >> 6;
    int col = lane & 15, kg = lane >> 4;

    for (int idx = tid; idx < 21 * 20; idx += 256) {
        int py = idx / 20, px = idx - py * 20;
        int gy = y0 - 2 + py, gx = x0 - 2 + px;
        ushort4 v = make_ushort4(0, 0, 0, 0);
        if (gy >= 0 && gy < 128 && gx >= 0 && gx < 128)
            v = *(const ushort4*)&xbf[(((size_t)b * 128 + gy) * 128 + gx) * 4];
        *(ushort4*)&in_s[idx * 4] = v;
    }
    for (int idx = tid; idx < 1632; idx += 256)
        *(bf16x8*)&w_s[idx * 8] = *(const bf16x8*)&w1r[idx * 8];
    __syncthreads();

    f32x4 acc[6][4];
    #pragma unroll
    for (int mt = 0; mt < 6; ++mt)
        #pragma unroll
        for (int n = 0; n < 4; ++n) acc[mt][n] = (f32x4){0.f, 0.f, 0.f, 0.f};

    #pragma unroll
    for (int ks = 0; ks < 4; ++ks) {
        int tap0 = ks * 8 + kg * 2;
        int ki = tap0 / 6, kj = tap0 - 6 * ki;
        bf16x8 bfrag[4];
        #pragma unroll
        for (int n = 0; n < 4; ++n) {
            int row = wv * 4 + n + ki;
            int ix = col + kj;
            const unsigned short* p = &in_s[(row * 20 + ix) * 4];
            union { bf16x8 v; uint2 u[2]; } tmp;
            tmp.u[0] = *(const uint2*)p;
            tmp.u[1] = *(const uint2*)(p + 4);
            bfrag[n] = tmp.v;
        }
        bf16x8 afrag[6];
        #pragma unroll
        for (int mt = 0; mt < 6; ++mt)
            afrag[mt] = *(const bf16x8*)&w_s[(mt * 16 + col) * 136 + ks * 32 + kg * 8];
        #pragma unroll
        for (int mt = 0; mt < 6; ++mt)
            #pragma unroll
            for (int n = 0; n < 4; ++n)
                acc[mt][n] = __builtin_amdgcn_mfma_f32_16x16x32_bf16(
                    afrag[mt], bfrag[n], acc[mt][n], 0, 0, 0);
    }

    float stdv = stdp[0], biasv = biasp[0];
    float inv2s2 = 1.f / (2.f * stdv * stdv);
    float a00 = alphap[0], a01 = alphap[1], a10 = alphap[2], a11 = alphap[3];
    int dx = col & 1;
    float ax0 = dx ? a01 : a00;
    float ax1 = dx ? a11 : a10;
    float pnv[4];
    #pragma unroll
    for (int n = 0; n < 4; ++n)
        pnv[n] = pn[((size_t)b * 128 + (y0 + wv * 4 + n)) * 128 + x0 + col];

    float sqa[2] = {0.f, 0.f};
    #pragma unroll
    for (int mt = 0; mt < 6; ++mt) {
        #pragma unroll
        for (int p2 = 0; p2 < 2; ++p2) {
            unsigned short res[4];
            #pragma unroll
            for (int r = 0; r < 4; ++r) {
                int o = mt * 16 + kg * 4 + r;
                float wno = wn[o];
                float d20 = fmaxf(pnv[2 * p2] + wno - 2.f * acc[mt][2 * p2][r], 0.f);
                float d21 = fmaxf(pnv[2 * p2 + 1] + wno - 2.f * acc[mt][2 * p2 + 1][r], 0.f);
                float g0 = __expf(-d20 * inv2s2);
                float g1 = __expf(-d21 * inv2s2);
                g0 = (g0 >= biasv) ? g0 : 0.f;
                g1 = (g1 >= biasv) ? g1 : 0.f;
                float s = ax0 * g0 + ax1 * g1;
                s += __shfl_xor(s, 1);
                res[r] = f2bf(0.25f * s);
                float vv = bf2f(res[r]);
                sqa[p2] += vv * vv;
            }
            if (dx == 0) {
                int yo = ty * 8 + wv * 2 + p2, xo = tx * 8 + (col >> 1);
                *(ushort4*)&out[(((size_t)b * 64 + yo) * 64 + xo) * 96 + mt * 16 + kg * 4] =
                    make_ushort4(res[0], res[1], res[2], res[3]);
            }
        }
    }
    // reduce sq across kg lanes (same pixel), write once
    #pragma unroll
    for (int p2 = 0; p2 < 2; ++p2) {
        float s = sqa[p2];
        s += __shfl_xor(s, 16);
        s += __shfl_xor(s, 32);
        if (dx == 0 && kg == 0) {
            int yo = ty * 8 + wv * 2 + p2, xo = tx * 8 + (col >> 1);
            sqout[((size_t)b * 64 + yo) * 64 + xo] = s;
        }
    }
}

// ---------- conv2: MFMA bf16, 2 waves x (96o x 64px), c-group 32, tap-pair dbuf ----------
__launch_bounds__(128, 2)
__global__ void conv2_mfma(const unsigned short* __restrict__ hin,  // [16][64][64][96] CL
                           const unsigned short* __restrict__ wt2,  // [3][26][192][32] bf16
                           const float* __restrict__ pn, const float* __restrict__ wn,
                           const float* __restrict__ stdp, const float* __restrict__ biasp,
                           const float* __restrict__ alphap,
                           const unsigned short* __restrict__ zerob,
                           unsigned short* __restrict__ hout) // [16][32][32][192] CL bf16
{
    __shared__ unsigned short in_s[240 * 32];      // 15360 B
    __shared__ unsigned short w_s[2][2 * 96 * 32]; // 24576 B

    int bid = blockIdx.x;
    int xt = bid & 3; bid >>= 2;
    int yt = bid & 7; bid >>= 3;
    int ot = bid & 1; int b = bid >> 1;
    int x0 = xt * 16, y0 = yt * 8, o0 = ot * 96;
    int tid = threadIdx.x;               // 0..127
    int lane = tid & 63, wave_n = tid >> 6;
    int col = lane & 15, kg = lane >> 4;

    f32x4 acc[6][4];
    #pragma unroll
    for (int mt = 0; mt < 6; ++mt)
        #pragma unroll
        for (int nt = 0; nt < 4; ++nt) acc[mt][nt] = (f32x4){0.f, 0.f, 0.f, 0.f};

    for (int cg = 0; cg < 3; ++cg) {
        // input c-slice [12][20][32]: 960 chunks, 8 iters of 128 (last: wave0 only)
        #pragma unroll
        for (int i = 0; i < 8; ++i) {
            int chunk = tid + i * 128;
            if (chunk < 960) {
                int px = chunk >> 2, c16 = chunk & 3;
                int iy = px / 20, ix = px - iy * 20;
                int gy = y0 - 2 + iy, gx = x0 - 2 + ix;
                const void* src = (gy >= 0 && gy < 64 && gx >= 0 && gx < 64)
                    ? (const void*)&hin[(((size_t)b * 64 + gy) * 64 + gx) * 96 + cg * 32 + c16 * 8]
                    : (const void*)zerob;
                gl16(&in_s[chunk * 8], src);
            }
        }
        // weight pair 0 -> buf0 (768 chunks = 6*128)
        #pragma unroll
        for (int i = 0; i < 6; ++i) {
            int chunk = tid + i * 128;
            int tp = chunk / 384, rem = chunk - tp * 384;
            gl16(&w_s[0][tp * 3072 + rem * 8],
                 &wt2[(((size_t)cg * 26 + tp) * 192 + o0) * 32 + rem * 8]);
        }
        __syncthreads();

        for (int pr = 0; pr < 13; ++pr) {
            int cur = pr & 1;
            if (pr < 12) {
                #pragma unroll
                for (int i = 0; i < 6; ++i) {
                    int chunk = tid + i * 128;
                    int tp = chunk / 384, rem = chunk - tp * 384;
                    gl16(&w_s[cur ^ 1][tp * 3072 + rem * 8],
                         &wt2[(((size_t)cg * 26 + (pr + 1) * 2 + tp) * 192 + o0) * 32 + rem * 8]);
                }
            }
            #pragma unroll
            for (int t2 = 0; t2 < 2; ++t2) {
                int tap = pr * 2 + t2;
                int ki = tap / 5, kj = tap - 5 * ki;
                if (tap >= 25) { ki = 0; kj = 0; }   // dummy tap: zero weights
                bf16x8 bfrag[4], afrag[6];
                #pragma unroll
                for (int nt = 0; nt < 4; ++nt) {
                    int yy = 2 * nt + (col >> 3) + ki;
                    int xx = wave_n * 8 + (col & 7) + kj;
                    bfrag[nt] = *(const bf16x8*)&in_s[(yy * 20 + xx) * 32 + kg * 8];
                }
                #pragma unroll
                for (int mt = 0; mt < 6; ++mt)
                    afrag[mt] = *(const bf16x8*)
                        &w_s[cur][(t2 * 96 + mt * 16 + col) * 32 + kg * 8];
                #pragma unroll
                for (int mt = 0; mt < 6; ++mt)
                    #pragma unroll
                    for (int nt = 0; nt < 4; ++nt)
                        acc[mt][nt] = __builtin_amdgcn_mfma_f32_16x16x32_bf16(
                            afrag[mt], bfrag[nt], acc[mt][nt], 0, 0, 0);
            }
            __syncthreads();
        }
    }

    // epilogue
    float stdv = stdp[0], biasv = biasp[0];
    float inv2s2 = 1.f / (2.f * stdv * stdv);
    float a_own = alphap[(col >> 3) * 2 + (col & 1)];
    #pragma unroll
    for (int nt = 0; nt < 4; ++nt) {
        int y = y0 + 2 * nt + (col >> 3);
        int x = x0 + wave_n * 8 + (col & 7);
        float pnv = pn[((size_t)b * 64 + y) * 64 + x];
        int yo = (y0 >> 1) + nt;
        int xo = x >> 1;
        #pragma unroll
        for (int mt = 0; mt < 6; ++mt) {
            int ob = o0 + mt * 16 + (kg << 2);
            unsigned short res[4];
            #pragma unroll
            for (int r = 0; r < 4; ++r) {
                float d2 = fmaxf(pnv + wn[ob + r] - 2.f * acc[mt][nt][r], 0.f);
                float g = __expf(-d2 * inv2s2);
                g = (g >= biasv) ? g : 0.f;
                g *= a_own;
                g += __shfl_xor(g, 1);
                g += __shfl_xor(g, 8);
                res[r] = f2bf(0.25f * g);
            }
            if (((col & 1) == 0) && ((col & 8) == 0)) {
                *(ushort4*)&hout[(((size_t)b * 32 + yo) * 32 + xo) * 192 + ob] =
                    make_ushort4(res[0], res[1], res[2], res[3]);
            }
        }
    }
}

// ---------- conv3: MFMA bf16, 2 waves x (96o x 32px), c-group 32, tap-pair dbuf ----------
__launch_bounds__(128, 2)
__global__ void conv3_mfma(const unsigned short* __restrict__ hin,  // [16][32][32][192] CL
                           const unsigned short* __restrict__ wt3,  // [6][10][192][32] bf16
                           const float* __restrict__ pn, const float* __restrict__ wn,
                           const float* __restrict__ stdp, const float* __restrict__ biasp,
                           const unsigned short* __restrict__ zerob,
                           unsigned short* __restrict__ hout) // [16][384*1024] bf16 CF
{
    __shared__ unsigned short in_s[512 * 8];       // [10][10][32] + pad; 8192 B
    __shared__ unsigned short w_s[2][2 * 96 * 32]; // 24576 B

    int bid = blockIdx.x;
    int xt = bid & 3; bid >>= 2;
    int yt = bid & 3; bid >>= 2;
    int ot = bid & 3; int b = bid >> 2;
    int x0 = xt * 8, y0 = yt * 8, o0 = ot * 96;
    int tid = threadIdx.x;               // 0..127
    int lane = tid & 63, wave_n = tid >> 6;
    int col = lane & 15, kg = lane >> 4;

    f32x4 acc[6][2];
    #pragma unroll
    for (int mt = 0; mt < 6; ++mt)
        #pragma unroll
        for (int nt = 0; nt < 2; ++nt) acc[mt][nt] = (f32x4){0.f, 0.f, 0.f, 0.f};

    for (int cg = 0; cg < 6; ++cg) {
        // input c-slice [10][10][32]: 400 real chunks; pad to 512 with zero loads
        #pragma unroll
        for (int i = 0; i < 4; ++i) {
            int chunk = tid + i * 128;
            int px = chunk >> 2, c16 = chunk & 3;
            const void* src = (const void*)zerob;
            if (px < 100) {
                int iy = px / 10, ix = px - iy * 10;
                int gy = y0 - 1 + iy, gx = x0 - 1 + ix;
                if (gy >= 0 && gy < 32 && gx >= 0 && gx < 32)
                    src = (const void*)&hin[(((size_t)b * 32 + gy) * 32 + gx) * 192 + cg * 32 + c16 * 8];
            }
            gl16(&in_s[chunk * 8], src);
        }
        // weight pair 0 -> buf0
        #pragma unroll
        for (int i = 0; i < 6; ++i) {
            int chunk = tid + i * 128;
            int tp = chunk / 384, rem = chunk - tp * 384;
            gl16(&w_s[0][tp * 3072 + rem * 8],
                 &wt3[(((size_t)cg * 10 + tp) * 192 + o0) * 32 + rem * 8]);
        }
        __syncthreads();

        for (int pr = 0; pr < 5; ++pr) {
            int cur = pr & 1;
            if (pr < 4) {
                #pragma unroll
                for (int i = 0; i < 6; ++i) {
                    int chunk = tid + i * 128;
                    int tp = chunk / 384, rem = chunk - tp * 384;
                    gl16(&w_s[cur ^ 1][tp * 3072 + rem * 8],
                         &wt3[(((size_t)cg * 10 + (pr + 1) * 2 + tp) * 192 + o0) * 32 + rem * 8]);
                }
            }
            #pragma unroll
            for (int t2 = 0; t2 < 2; ++t2) {
                int tap = pr * 2 + t2;
                int ki = tap / 3, kj = tap - 3 * ki;
                if (tap >= 9) { ki = 0; kj = 0; }    // dummy tap: zero weights
                bf16x8 bfrag[2], afrag[6];
                #pragma unroll
                for (int nt = 0; nt < 2; ++nt) {
                    int yy = wave_n * 4 + 2 * nt + (col >> 3) + ki;
                    int xx = (col & 7) + kj;
                    bfrag[nt] = *(const bf16x8*)&in_s[(yy * 10 + xx) * 32 + kg * 8];
                }
                #pragma unroll
                for (int mt = 0; mt < 6; ++mt)
                    afrag[mt] = *(const bf16x8*)
                        &w_s[cur][(t2 * 96 + mt * 16 + col) * 32 + kg * 8];
                #pragma unroll
                for (int mt = 0; mt < 6; ++mt)
                    #pragma unroll
                    for (int nt = 0; nt < 2; ++nt)
                        acc[mt][nt] = __builtin_amdgcn_mfma_f32_16x16x32_bf16(
                            afrag[mt], bfrag[nt], acc[mt][nt], 0, 0, 0);
            }
            __syncthreads();
        }
    }

    float stdv = stdp[0], biasv = biasp[0];
    float inv2s2 = 1.f / (2.f * stdv * stdv);
    #pragma unroll
    for (int nt = 0; nt < 2; ++nt) {
        int y = y0 + wave_n * 4 + 2 * nt + (col >> 3);
        int x = x0 + (col & 7);
        float pnv = pn[((size_t)b * 32 + y) * 32 + x];
        #pragma unroll
        for (int mt = 0; mt < 6; ++mt) {
            int ob = o0 + mt * 16 + (kg << 2);
            #pragma unroll
            for (int r = 0; r < 4; ++r) {
                float d2 = fmaxf(pnv + wn[ob + r] - 2.f * acc[mt][nt][r], 0.f);
                float g = __expf(-d2 * inv2s2);
                g = (g >= biasv) ? g : 0.f;
                hout[((size_t)b * 384 + ob + r) * 1024 + y * 32 + x] = f2bf(g);
            }
        }
    }
}

// ---------- FC: MFMA over K-chunks, prefetched fw loads ----------
__launch_bounds__(256, 4)
__global__ void fc_mfma(const unsigned short* __restrict__ h3bf,
                        const float* __restrict__ fw,
                        float* __restrict__ fcp) // [768][112][16]
{
    __shared__ unsigned short h3s[16 * 520];
    __shared__ unsigned short fws[16 * 520];
    __shared__ float red[4][16][16];
    const size_t KI = 393216;
    int ch = blockIdx.x;
    int i0 = ch * 512;
    int tid = threadIdx.x;
    int lane = tid & 63, wv = tid >> 6;
    int col = lane & 15, kg = lane >> 4;

    #pragma unroll
    for (int it = 0; it < 4; ++it) {
        int c = tid + it * 256;
        int b = c >> 6, off = (c & 63) * 8;
        *(bf16x8*)&h3s[b * 520 + off] = *(const bf16x8*)&h3bf[(size_t)b * KI + i0 + off];
    }

    float4 pre[8];
    #pragma unroll
    for (int it = 0; it < 8; ++it) {
        int c = tid + it * 256;
        int row = c >> 7, off4 = (c & 127) * 4;
        pre[it] = (row < 100) ? *(const float4*)&fw[(size_t)row * KI + i0 + off4]
                              : make_float4(0.f, 0.f, 0.f, 0.f);
    }

    for (int jt = 0; jt < 7; ++jt) {
        int j0 = jt * 16;
        #pragma unroll
        for (int it = 0; it < 8; ++it) {
            int c = tid + it * 256;
            int row = c >> 7, off4 = (c & 127) * 4;
            *(ushort4*)&fws[row * 520 + off4] =
                make_ushort4(f2bf(pre[it].x), f2bf(pre[it].y), f2bf(pre[it].z), f2bf(pre[it].w));
        }
        if (jt < 6) {
            #pragma unroll
            for (int it = 0; it < 8; ++it) {
                int c = tid + it * 256;
                int row = c >> 7, off4 = (c & 127) * 4;
                int j = j0 + 16 + row;
                pre[it] = (j < 100) ? *(const float4*)&fw[(size_t)j * KI + i0 + off4]
                                    : make_float4(0.f, 0.f, 0.f, 0.f);
            }
        }
        __syncthreads();
        f32x4 acc = (f32x4){0.f, 0.f, 0.f, 0.f};
        #pragma unroll
        for (int s = 0; s < 4; ++s) {
            int k = wv * 128 + s * 32 + kg * 8;
            bf16x8 af = *(const bf16x8*)&fws[col * 520 + k];
            bf16x8 bg = *(const bf16x8*)&h3s[col * 520 + k];
            acc = __builtin_amdgcn_mfma_f32_16x16x32_bf16(af, bg, acc, 0, 0, 0);
        }
        #pragma unroll
        for (int r = 0; r < 4; ++r) red[wv][kg * 4 + r][col] = acc[r];
        __syncthreads();
        int j = tid >> 4, bb = tid & 15;
        float s = red[0][j][bb] + red[1][j][bb] + red[2][j][bb] + red[3][j][bb];
        fcp[((size_t)ch * 112 + j0 + j) * 16 + bb] = s;
    }
}

__global__ void fc_final(const float* __restrict__ fcp, const float* __restrict__ fb,
                         float* __restrict__ outp) {
    int j = blockIdx.x;
    int lane = threadIdx.x;
    float acc[16];
    #pragma unroll
    for (int b = 0; b < 16; ++b) acc[b] = 0.f;
    for (int ch = lane; ch < 768; ch += 64) {
        const float* p = &fcp[((size_t)ch * 112 + j) * 16];
        #pragma unroll
        for (int b = 0; b < 16; ++b) acc[b] += p[b];
    }
    #pragma unroll
    for (int off = 32; off >= 1; off >>= 1)
        #pragma unroll
        for (int b = 0; b < 16; ++b) acc[b] += __shfl_down(acc[b], off);
    if (lane == 0) {
        float bj = fb[j];
        #pragma unroll
        for (int b = 0; b < 16; ++b) outp[b * 100 + j] = bj + acc[b];
    }
}

// ---------- launch ----------
extern "C" void kernel_launch(void* const* d_in, const int* in_sizes, int n_in,
                              void* d_out, int out_size, void* d_ws, size_t ws_size,
                              hipStream_t stream) {
    const float* x      = (const float*)d_in[0];
    const float* w1     = (const float*)d_in[1];
    const float* std1   = (const float*)d_in[2];
    const float* bias1  = (const float*)d_in[3];
    const float* alpha1 = (const float*)d_in[4];
    const float* w2     = (const float*)d_in[5];
    const float* std2   = (const float*)d_in[6];
    const float* bias2  = (const float*)d_in[7];
    const float* alpha2 = (const float*)d_in[8];
    const float* w3     = (const float*)d_in[9];
    const float* std3   = (const float*)d_in[10];
    const float* bias3  = (const float*)d_in[11];
    const float* fc_w   = (const float*)d_in[12];
    const float* fc_b   = (const float*)d_in[13];
    float* out = (float*)d_out;
    float* ws  = (float*)d_ws;

    // float region
    float* pn1   = ws;                  // 262144
    float* sbuf  = pn1 + 262144;        // 262144
    float* pn2   = sbuf + 262144;       // 65536
    float* pn3   = pn2 + 65536;         // 16384
    float* fcp   = pn3 + 16384;         // 1376256
    float* wn1   = fcp + 1376256;       // 96
    float* wn2   = wn1 + 96;            // 192
    float* wn3   = wn2 + 192;           // 384
    float* rest  = wn3 + 384 + 32;      // 16B-aligned boundary
    // ushort region (all multiples of 8 -> 16B alignment preserved)
    unsigned short* h1bf = (unsigned short*)rest;  // 6291456
    unsigned short* h2bf = h1bf + 6291456;         // 3145728
    unsigned short* h3bf = h2bf + 3145728;         // 6291456
    unsigned short* xbf  = h3bf + 6291456;         // 1048576
    unsigned short* w1r  = xbf + 1048576;          // 13056
    unsigned short* w2r  = w1r + 13056;            // 479232
    unsigned short* w3r  = w2r + 479232;           // 368640
    unsigned short* zerob = w3r + 368640;          // 64

    dim3 B(TPB);

    // ---- prep ----
    xbf_prep_sq<<<dim3(1024), B, 0, stream>>>(x, xbf, sbuf);
    wt_all<<<dim3(3364), B, 0, stream>>>(w1, w2, w3, w1r, w2r, w3r, zerob);
    wn_all<<<dim3(672), dim3(64), 0, stream>>>(w1, w2, w3, wn1, wn2, wn3);

    // ---- block 1 ----
    win_sum_kernel<5, 2><<<dim3(1024), B, 0, stream>>>(sbuf, pn1, 128, 128);
    conv1_mfma<<<dim3(1024), B, 0, stream>>>(xbf, w1r, pn1, wn1, std1, bias1, alpha1,
                                             h1bf, sbuf);

    // ---- block 2 ----
    win_sum_kernel<5, 2><<<dim3(256), B, 0, stream>>>(sbuf, pn2, 64, 64);
    conv2_mfma<<<dim3(1024), dim3(128), 0, stream>>>(
        h1bf, w2r, pn2, wn2, std2, bias2, alpha2, zerob, h2bf);

    // ---- block 3 ----
    sq_cl_kernel<192><<<dim3(64), B, 0, stream>>>(h2bf, sbuf);
    win_sum_kernel<3, 1><<<dim3(64), B, 0, stream>>>(sbuf, pn3, 32, 32);
    conv3_mfma<<<dim3(1024), dim3(128), 0, stream>>>(
        h2bf, w3r, pn3, wn3, std3, bias3, zerob, h3bf);

    // ---- fc ----
    fc_mfma<<<dim3(768), B, 0, stream>>>(h3bf, fc_w, fcp);
    fc_final<<<dim3(100), dim3(64), 0, stream>>>(fcp, fc_b, out);
}

// Round 7
// 177.585 us; speedup vs baseline: 7.6861x; 1.0630x over previous
//
#include <hip/hip_runtime.h>

#define TPB 256

typedef short bf16x8 __attribute__((ext_vector_type(8)));
typedef float f32x4 __attribute__((ext_vector_type(4)));

__device__ inline unsigned short f2bf(float f) {
    unsigned int u = __float_as_uint(f);
    unsigned int r = (u + 0x7fffu + ((u >> 16) & 1u)) >> 16;
    return (unsigned short)r;
}
__device__ inline float bf2f(unsigned short h) {
    return __uint_as_float(((unsigned int)h) << 16);
}

// async global->LDS 16B copy (dest: linear wave-order, src: per-lane)
__device__ __forceinline__ void gl16(void* lds, const void* g) {
    __builtin_amdgcn_global_load_lds(
        (const __attribute__((address_space(1))) unsigned int*)g,
        (__attribute__((address_space(3))) unsigned int*)lds, 16, 0, 0);
}

// ---------- small kernels ----------

// x [16,3,128,128] fp32 CF -> xbf [16][128][128][4] bf16 + sq plane (fp32)
__global__ void xbf_prep_sq(const float* __restrict__ x, unsigned short* __restrict__ xbf,
                            float* __restrict__ sq) {
    int idx = blockIdx.x * TPB + threadIdx.x;
    int b = idx >> 14, px = idx & 16383;
    const float* xb = x + (size_t)b * 3 * 16384 + px;
    float v0 = xb[0], v1 = xb[16384], v2 = xb[32768];
    ushort4 v;
    v.x = f2bf(v0); v.y = f2bf(v1); v.z = f2bf(v2); v.w = 0;
    *(ushort4*)&xbf[(size_t)idx * 4] = v;
    sq[idx] = v0 * v0 + v1 * v1 + v2 * v2;
}

template<int K, int PAD>
__global__ void win_sum_kernel(const float* __restrict__ s, float* __restrict__ pn,
                               int H, int W) {
    int idx = blockIdx.x * TPB + threadIdx.x;
    int b = idx / (H * W); int rem = idx - b * H * W;
    int y = rem / W, x = rem - y * W;
    const float* sb = s + (size_t)b * H * W;
    float acc = 0.f;
    #pragma unroll
    for (int ki = 0; ki < K; ++ki) {
        int yy = y - PAD + ki;
        if (yy < 0 || yy >= H) continue;
        #pragma unroll
        for (int kj = 0; kj < K; ++kj) {
            int xx = x - PAD + kj;
            if (xx < 0 || xx >= W) continue;
            acc += sb[yy * W + xx];
        }
    }
    pn[idx] = acc;
}

// fused: sq over 192 channels (bf16 CL) + 3x3 zero-pad window sum; one block per image
__global__ void sq_win3(const unsigned short* __restrict__ h2bf, float* __restrict__ pn3) {
    __shared__ float s[32][33];
    int b = blockIdx.x;
    int tid = threadIdx.x;
    #pragma unroll
    for (int i = 0; i < 4; ++i) {
        int px = tid + i * 256;
        const unsigned short* p = h2bf + ((size_t)b * 1024 + px) * 192;
        float acc = 0.f;
        #pragma unroll
        for (int c = 0; c < 192; c += 8) {
            bf16x8 v = *(const bf16x8*)&p[c];
            #pragma unroll
            for (int j = 0; j < 8; ++j) { float f = bf2f((unsigned short)v[j]); acc += f * f; }
        }
        s[px >> 5][px & 31] = acc;
    }
    __syncthreads();
    #pragma unroll
    for (int i = 0; i < 4; ++i) {
        int px = tid + i * 256;
        int y = px >> 5, x = px & 31;
        float a = 0.f;
        #pragma unroll
        for (int dy = -1; dy <= 1; ++dy) {
            int yy = y + dy;
            if (yy < 0 || yy >= 32) continue;
            #pragma unroll
            for (int dx = -1; dx <= 1; ++dx) {
                int xx = x + dx;
                if (xx < 0 || xx >= 32) continue;
                a += s[yy][xx];
            }
        }
        pn3[(size_t)b * 1024 + px] = a;
    }
}

// all three layers' weight row norms; 672 blocks x 64 lanes
__global__ void wn_all(const float* __restrict__ w1, const float* __restrict__ w2,
                       const float* __restrict__ w3,
                       float* __restrict__ wn1, float* __restrict__ wn2,
                       float* __restrict__ wn3) {
    int o = blockIdx.x;
    const float* row; float* dst; int D;
    if (o < 96)       { row = w1 + (size_t)o * 75;           D = 75;   dst = wn1 + o; }
    else if (o < 288) { int r = o - 96;  row = w2 + (size_t)r * 2400; D = 2400; dst = wn2 + r; }
    else              { int r = o - 288; row = w3 + (size_t)r * 1728; D = 1728; dst = wn3 + r; }
    int lane = threadIdx.x;
    float acc = 0.f;
    for (int i = lane; i < D; i += 64) { float v = row[i]; acc += v * v; }
    #pragma unroll
    for (int off = 32; off >= 1; off >>= 1) acc += __shfl_down(acc, off);
    if (lane == 0) *dst = acc;
}

// all weight reorders + zerob in one kernel
__global__ void wt_all(const float* __restrict__ w1, const float* __restrict__ w2,
                       const float* __restrict__ w3,
                       unsigned short* __restrict__ w1r, unsigned short* __restrict__ w2r,
                       unsigned short* __restrict__ w3r, unsigned short* __restrict__ zerob) {
    int idx = blockIdx.x * TPB + threadIdx.x;
    if (idx < 13056) {
        int o = idx / 136, d = idx - o * 136;
        int tp = d >> 2, c = d & 3;
        float v = 0.f;
        if (tp < 30 && c < 3) {
            int ki = tp / 6, kj = tp - 6 * ki;
            if (kj < 5) v = w1[o * 75 + c * 25 + ki * 5 + kj];
        }
        w1r[idx] = f2bf(v);
    } else if (idx < 13056 + 479232) {
        int i = idx - 13056;
        int c = i & 31; int r = i >> 5;
        int o = r % 192; r /= 192;
        int tap = r % 26; int cg = r / 26;
        float v = 0.f;
        if (tap < 25) v = w2[((size_t)o * 96 + cg * 32 + c) * 25 + tap];
        w2r[i] = f2bf(v);
    } else if (idx < 13056 + 479232 + 368640) {
        int i = idx - 13056 - 479232;
        int c = i & 31; int r = i >> 5;
        int o = r % 192; r /= 192;
        int tap = r % 10; int cg = r / 10;
        float v = 0.f;
        if (tap < 9) v = w3[((size_t)o * 192 + cg * 32 + c) * 9 + tap];
        w3r[i] = f2bf(v);
    } else if (idx < 13056 + 479232 + 368640 + 64) {
        zerob[idx - 13056 - 479232 - 368640] = 0;
    }
}

// ---------- conv1: MFMA bf16, K=128 (32 taps x 4c); epilogue also emits sq plane ----------
__launch_bounds__(256, 2)
__global__ void conv1_mfma(const unsigned short* __restrict__ xbf,
                           const unsigned short* __restrict__ w1r,
                           const float* __restrict__ pn, const float* __restrict__ wn,
                           const float* __restrict__ stdp, const float* __restrict__ biasp,
                           const float* __restrict__ alphap,
                           unsigned short* __restrict__ out,  // [16][64][64][96] bf16 CL
                           float* __restrict__ sqout)         // [16][64][64] fp32
{
    __shared__ unsigned short in_s[22 * 20 * 4];
    __shared__ unsigned short w_s[96 * 136];

    int bid = blockIdx.x;
    int tx = bid & 7; bid >>= 3;
    int ty = bid & 7; bid >>= 3;
    int b = bid;
    int x0 = tx * 16, y0 = ty * 16;
    int tid = threadIdx.x;
    int lane = tid & 63, wv = tid >> 6;
    int col = lane & 15, kg = lane >> 4;

    for (int idx = tid; idx < 21 * 20; idx += 256) {
        int py = idx / 20, px = idx - py * 20;
        int gy = y0 - 2 + py, gx = x0 - 2 + px;
        ushort4 v = make_ushort4(0, 0, 0, 0);
        if (gy >= 0 && gy < 128 && gx >= 0 && gx < 128)
            v = *(const ushort4*)&xbf[(((size_t)b * 128 + gy) * 128 + gx) * 4];
        *(ushort4*)&in_s[idx * 4] = v;
    }
    for (int idx = tid; idx < 1632; idx += 256)
        *(bf16x8*)&w_s[idx * 8] = *(const bf16x8*)&w1r[idx * 8];
    __syncthreads();

    f32x4 acc[6][4];
    #pragma unroll
    for (int mt = 0; mt < 6; ++mt)
        #pragma unroll
        for (int n = 0; n < 4; ++n) acc[mt][n] = (f32x4){0.f, 0.f, 0.f, 0.f};

    #pragma unroll
    for (int ks = 0; ks < 4; ++ks) {
        int tap0 = ks * 8 + kg * 2;
        int ki = tap0 / 6, kj = tap0 - 6 * ki;
        bf16x8 bfrag[4];
        #pragma unroll
        for (int n = 0; n < 4; ++n) {
            int row = wv * 4 + n + ki;
            int ix = col + kj;
            const unsigned short* p = &in_s[(row * 20 + ix) * 4];
            union { bf16x8 v; uint2 u[2]; } tmp;
            tmp.u[0] = *(const uint2*)p;
            tmp.u[1] = *(const uint2*)(p + 4);
            bfrag[n] = tmp.v;
        }
        bf16x8 afrag[6];
        #pragma unroll
        for (int mt = 0; mt < 6; ++mt)
            afrag[mt] = *(const bf16x8*)&w_s[(mt * 16 + col) * 136 + ks * 32 + kg * 8];
        #pragma unroll
        for (int mt = 0; mt < 6; ++mt)
            #pragma unroll
            for (int n = 0; n < 4; ++n)
                acc[mt][n] = __builtin_amdgcn_mfma_f32_16x16x32_bf16(
                    afrag[mt], bfrag[n], acc[mt][n], 0, 0, 0);
    }

    float stdv = stdp[0], biasv = biasp[0];
    float inv2s2 = 1.f / (2.f * stdv * stdv);
    float a00 = alphap[0], a01 = alphap[1], a10 = alphap[2], a11 = alphap[3];
    int dx = col & 1;
    float ax0 = dx ? a01 : a00;
    float ax1 = dx ? a11 : a10;
    float pnv[4];
    #pragma unroll
    for (int n = 0; n < 4; ++n)
        pnv[n] = pn[((size_t)b * 128 + (y0 + wv * 4 + n)) * 128 + x0 + col];

    float sqa[2] = {0.f, 0.f};
    #pragma unroll
    for (int mt = 0; mt < 6; ++mt) {
        #pragma unroll
        for (int p2 = 0; p2 < 2; ++p2) {
            unsigned short res[4];
            #pragma unroll
            for (int r = 0; r < 4; ++r) {
                int o = mt * 16 + kg * 4 + r;
                float wno = wn[o];
                float d20 = fmaxf(pnv[2 * p2] + wno - 2.f * acc[mt][2 * p2][r], 0.f);
                float d21 = fmaxf(pnv[2 * p2 + 1] + wno - 2.f * acc[mt][2 * p2 + 1][r], 0.f);
                float g0 = __expf(-d20 * inv2s2);
                float g1 = __expf(-d21 * inv2s2);
                g0 = (g0 >= biasv) ? g0 : 0.f;
                g1 = (g1 >= biasv) ? g1 : 0.f;
                float s = ax0 * g0 + ax1 * g1;
                s += __shfl_xor(s, 1);
                res[r] = f2bf(0.25f * s);
                float vv = bf2f(res[r]);
                sqa[p2] += vv * vv;
            }
            if (dx == 0) {
                int yo = ty * 8 + wv * 2 + p2, xo = tx * 8 + (col >> 1);
                *(ushort4*)&out[(((size_t)b * 64 + yo) * 64 + xo) * 96 + mt * 16 + kg * 4] =
                    make_ushort4(res[0], res[1], res[2], res[3]);
            }
        }
    }
    #pragma unroll
    for (int p2 = 0; p2 < 2; ++p2) {
        float s = sqa[p2];
        s += __shfl_xor(s, 16);
        s += __shfl_xor(s, 32);
        if (dx == 0 && kg == 0) {
            int yo = ty * 8 + wv * 2 + p2, xo = tx * 8 + (col >> 1);
            sqout[((size_t)b * 64 + yo) * 64 + xo] = s;
        }
    }
}

// ---------- conv2: MFMA bf16, 2 waves x (96o x 64px), c-group 32, tap-pair dbuf ----------
__launch_bounds__(128, 2)
__global__ void conv2_mfma(const unsigned short* __restrict__ hin,
                           const unsigned short* __restrict__ wt2,
                           const float* __restrict__ pn, const float* __restrict__ wn,
                           const float* __restrict__ stdp, const float* __restrict__ biasp,
                           const float* __restrict__ alphap,
                           const unsigned short* __restrict__ zerob,
                           unsigned short* __restrict__ hout) // [16][32][32][192] CL bf16
{
    __shared__ unsigned short in_s[240 * 32];
    __shared__ unsigned short w_s[2][2 * 96 * 32];

    int bid = blockIdx.x;
    int xt = bid & 3; bid >>= 2;
    int yt = bid & 7; bid >>= 3;
    int ot = bid & 1; int b = bid >> 1;
    int x0 = xt * 16, y0 = yt * 8, o0 = ot * 96;
    int tid = threadIdx.x;
    int lane = tid & 63, wave_n = tid >> 6;
    int col = lane & 15, kg = lane >> 4;

    f32x4 acc[6][4];
    #pragma unroll
    for (int mt = 0; mt < 6; ++mt)
        #pragma unroll
        for (int nt = 0; nt < 4; ++nt) acc[mt][nt] = (f32x4){0.f, 0.f, 0.f, 0.f};

    for (int cg = 0; cg < 3; ++cg) {
        #pragma unroll
        for (int i = 0; i < 8; ++i) {
            int chunk = tid + i * 128;
            if (chunk < 960) {
                int px = chunk >> 2, c16 = chunk & 3;
                int iy = px / 20, ix = px - iy * 20;
                int gy = y0 - 2 + iy, gx = x0 - 2 + ix;
                const void* src = (gy >= 0 && gy < 64 && gx >= 0 && gx < 64)
                    ? (const void*)&hin[(((size_t)b * 64 + gy) * 64 + gx) * 96 + cg * 32 + c16 * 8]
                    : (const void*)zerob;
                gl16(&in_s[chunk * 8], src);
            }
        }
        #pragma unroll
        for (int i = 0; i < 6; ++i) {
            int chunk = tid + i * 128;
            int tp = chunk / 384, rem = chunk - tp * 384;
            gl16(&w_s[0][tp * 3072 + rem * 8],
                 &wt2[(((size_t)cg * 26 + tp) * 192 + o0) * 32 + rem * 8]);
        }
        __syncthreads();

        for (int pr = 0; pr < 13; ++pr) {
            int cur = pr & 1;
            if (pr < 12) {
                #pragma unroll
                for (int i = 0; i < 6; ++i) {
                    int chunk = tid + i * 128;
                    int tp = chunk / 384, rem = chunk - tp * 384;
                    gl16(&w_s[cur ^ 1][tp * 3072 + rem * 8],
                         &wt2[(((size_t)cg * 26 + (pr + 1) * 2 + tp) * 192 + o0) * 32 + rem * 8]);
                }
            }
            #pragma unroll
            for (int t2 = 0; t2 < 2; ++t2) {
                int tap = pr * 2 + t2;
                int ki = tap / 5, kj = tap - 5 * ki;
                if (tap >= 25) { ki = 0; kj = 0; }
                bf16x8 bfrag[4], afrag[6];
                #pragma unroll
                for (int nt = 0; nt < 4; ++nt) {
                    int yy = 2 * nt + (col >> 3) + ki;
                    int xx = wave_n * 8 + (col & 7) + kj;
                    bfrag[nt] = *(const bf16x8*)&in_s[(yy * 20 + xx) * 32 + kg * 8];
                }
                #pragma unroll
                for (int mt = 0; mt < 6; ++mt)
                    afrag[mt] = *(const bf16x8*)
                        &w_s[cur][(t2 * 96 + mt * 16 + col) * 32 + kg * 8];
                #pragma unroll
                for (int mt = 0; mt < 6; ++mt)
                    #pragma unroll
                    for (int nt = 0; nt < 4; ++nt)
                        acc[mt][nt] = __builtin_amdgcn_mfma_f32_16x16x32_bf16(
                            afrag[mt], bfrag[nt], acc[mt][nt], 0, 0, 0);
            }
            __syncthreads();
        }
    }

    float stdv = stdp[0], biasv = biasp[0];
    float inv2s2 = 1.f / (2.f * stdv * stdv);
    float a_own = alphap[(col >> 3) * 2 + (col & 1)];
    #pragma unroll
    for (int nt = 0; nt < 4; ++nt) {
        int y = y0 + 2 * nt + (col >> 3);
        int x = x0 + wave_n * 8 + (col & 7);
        float pnv = pn[((size_t)b * 64 + y) * 64 + x];
        int yo = (y0 >> 1) + nt;
        int xo = x >> 1;
        #pragma unroll
        for (int mt = 0; mt < 6; ++mt) {
            int ob = o0 + mt * 16 + (kg << 2);
            unsigned short res[4];
            #pragma unroll
            for (int r = 0; r < 4; ++r) {
                float d2 = fmaxf(pnv + wn[ob + r] - 2.f * acc[mt][nt][r], 0.f);
                float g = __expf(-d2 * inv2s2);
                g = (g >= biasv) ? g : 0.f;
                g *= a_own;
                g += __shfl_xor(g, 1);
                g += __shfl_xor(g, 8);
                res[r] = f2bf(0.25f * g);
            }
            if (((col & 1) == 0) && ((col & 8) == 0)) {
                *(ushort4*)&hout[(((size_t)b * 32 + yo) * 32 + xo) * 192 + ob] =
                    make_ushort4(res[0], res[1], res[2], res[3]);
            }
        }
    }
}

// ---------- conv3: MFMA bf16, 2 waves x (96o x 32px), c-group 32, tap-pair dbuf ----------
__launch_bounds__(128, 2)
__global__ void conv3_mfma(const unsigned short* __restrict__ hin,
                           const unsigned short* __restrict__ wt3,
                           const float* __restrict__ pn, const float* __restrict__ wn,
                           const float* __restrict__ stdp, const float* __restrict__ biasp,
                           const unsigned short* __restrict__ zerob,
                           unsigned short* __restrict__ hout) // [16][384*1024] bf16 CF
{
    __shared__ unsigned short in_s[512 * 8];
    __shared__ unsigned short w_s[2][2 * 96 * 32];

    int bid = blockIdx.x;
    int xt = bid & 3; bid >>= 2;
    int yt = bid & 3; bid >>= 2;
    int ot = bid & 3; int b = bid >> 2;
    int x0 = xt * 8, y0 = yt * 8, o0 = ot * 96;
    int tid = threadIdx.x;
    int lane = tid & 63, wave_n = tid >> 6;
    int col = lane & 15, kg = lane >> 4;

    f32x4 acc[6][2];
    #pragma unroll
    for (int mt = 0; mt < 6; ++mt)
        #pragma unroll
        for (int nt = 0; nt < 2; ++nt) acc[mt][nt] = (f32x4){0.f, 0.f, 0.f, 0.f};

    for (int cg = 0; cg < 6; ++cg) {
        #pragma unroll
        for (int i = 0; i < 4; ++i) {
            int chunk = tid + i * 128;
            int px = chunk >> 2, c16 = chunk & 3;
            const void* src = (const void*)zerob;
            if (px < 100) {
                int iy = px / 10, ix = px - iy * 10;
                int gy = y0 - 1 + iy, gx = x0 - 1 + ix;
                if (gy >= 0 && gy < 32 && gx >= 0 && gx < 32)
                    src = (const void*)&hin[(((size_t)b * 32 + gy) * 32 + gx) * 192 + cg * 32 + c16 * 8];
            }
            gl16(&in_s[chunk * 8], src);
        }
        #pragma unroll
        for (int i = 0; i < 6; ++i) {
            int chunk = tid + i * 128;
            int tp = chunk / 384, rem = chunk - tp * 384;
            gl16(&w_s[0][tp * 3072 + rem * 8],
                 &wt3[(((size_t)cg * 10 + tp) * 192 + o0) * 32 + rem * 8]);
        }
        __syncthreads();

        for (int pr = 0; pr < 5; ++pr) {
            int cur = pr & 1;
            if (pr < 4) {
                #pragma unroll
                for (int i = 0; i < 6; ++i) {
                    int chunk = tid + i * 128;
                    int tp = chunk / 384, rem = chunk - tp * 384;
                    gl16(&w_s[cur ^ 1][tp * 3072 + rem * 8],
                         &wt3[(((size_t)cg * 10 + (pr + 1) * 2 + tp) * 192 + o0) * 32 + rem * 8]);
                }
            }
            #pragma unroll
            for (int t2 = 0; t2 < 2; ++t2) {
                int tap = pr * 2 + t2;
                int ki = tap / 3, kj = tap - 3 * ki;
                if (tap >= 9) { ki = 0; kj = 0; }
                bf16x8 bfrag[2], afrag[6];
                #pragma unroll
                for (int nt = 0; nt < 2; ++nt) {
                    int yy = wave_n * 4 + 2 * nt + (col >> 3) + ki;
                    int xx = (col & 7) + kj;
                    bfrag[nt] = *(const bf16x8*)&in_s[(yy * 10 + xx) * 32 + kg * 8];
                }
                #pragma unroll
                for (int mt = 0; mt < 6; ++mt)
                    afrag[mt] = *(const bf16x8*)
                        &w_s[cur][(t2 * 96 + mt * 16 + col) * 32 + kg * 8];
                #pragma unroll
                for (int mt = 0; mt < 6; ++mt)
                    #pragma unroll
                    for (int nt = 0; nt < 2; ++nt)
                        acc[mt][nt] = __builtin_amdgcn_mfma_f32_16x16x32_bf16(
                            afrag[mt], bfrag[nt], acc[mt][nt], 0, 0, 0);
            }
            __syncthreads();
        }
    }

    float stdv = stdp[0], biasv = biasp[0];
    float inv2s2 = 1.f / (2.f * stdv * stdv);
    #pragma unroll
    for (int nt = 0; nt < 2; ++nt) {
        int y = y0 + wave_n * 4 + 2 * nt + (col >> 3);
        int x = x0 + (col & 7);
        float pnv = pn[((size_t)b * 32 + y) * 32 + x];
        #pragma unroll
        for (int mt = 0; mt < 6; ++mt) {
            int ob = o0 + mt * 16 + (kg << 2);
            #pragma unroll
            for (int r = 0; r < 4; ++r) {
                float d2 = fmaxf(pnv + wn[ob + r] - 2.f * acc[mt][nt][r], 0.f);
                float g = __expf(-d2 * inv2s2);
                g = (g >= biasv) ? g : 0.f;
                hout[((size_t)b * 384 + ob + r) * 1024 + y * 32 + x] = f2bf(g);
            }
        }
    }
}

// ---------- FC: MFMA over K-chunks with exact zero-chunk skip ----------
__launch_bounds__(256, 4)
__global__ void fc_mfma(const unsigned short* __restrict__ h3bf,
                        const float* __restrict__ fw,
                        float* __restrict__ fcp,  // [768][112][16]
                        int* __restrict__ flags)  // [768]
{
    __shared__ unsigned short h3s[16 * 520];
    __shared__ unsigned short fws[16 * 520];
    __shared__ float red[4][16][16];
    __shared__ int s_nz[4];
    const size_t KI = 393216;
    int ch = blockIdx.x;
    int i0 = ch * 512;
    int tid = threadIdx.x;
    int lane = tid & 63, wv = tid >> 6;
    int col = lane & 15, kg = lane >> 4;

    // stage h3 chunk (bf16), tracking nonzero bits
    unsigned int nzbits = 0;
    #pragma unroll
    for (int it = 0; it < 4; ++it) {
        int c = tid + it * 256;
        int b = c >> 6, off = (c & 63) * 8;
        bf16x8 v = *(const bf16x8*)&h3bf[(size_t)b * KI + i0 + off];
        union { bf16x8 s; unsigned int u[4]; } cv; cv.s = v;
        nzbits |= cv.u[0] | cv.u[1] | cv.u[2] | cv.u[3];
        *(bf16x8*)&h3s[b * 520 + off] = v;
    }
    bool any = __any(nzbits != 0);
    if (lane == 0) s_nz[wv] = any ? 1 : 0;
    __syncthreads();
    int anyall = s_nz[0] | s_nz[1] | s_nz[2] | s_nz[3];
    if (!anyall) {
        // exact: this chunk contributes 0 to every output; skip all fw traffic
        if (tid == 0) flags[ch] = 0;
        return;
    }
    if (tid == 0) flags[ch] = 1;

    float4 pre[8];
    #pragma unroll
    for (int it = 0; it < 8; ++it) {
        int c = tid + it * 256;
        int row = c >> 7, off4 = (c & 127) * 4;
        pre[it] = (row < 100) ? *(const float4*)&fw[(size_t)row * KI + i0 + off4]
                              : make_float4(0.f, 0.f, 0.f, 0.f);
    }

    for (int jt = 0; jt < 7; ++jt) {
        int j0 = jt * 16;
        #pragma unroll
        for (int it = 0; it < 8; ++it) {
            int c = tid + it * 256;
            int row = c >> 7, off4 = (c & 127) * 4;
            *(ushort4*)&fws[row * 520 + off4] =
                make_ushort4(f2bf(pre[it].x), f2bf(pre[it].y), f2bf(pre[it].z), f2bf(pre[it].w));
        }
        if (jt < 6) {
            #pragma unroll
            for (int it = 0; it < 8; ++it) {
                int c = tid + it * 256;
                int row = c >> 7, off4 = (c & 127) * 4;
                int j = j0 + 16 + row;
                pre[it] = (j < 100) ? *(const float4*)&fw[(size_t)j * KI + i0 + off4]
                                    : make_float4(0.f, 0.f, 0.f, 0.f);
            }
        }
        __syncthreads();
        f32x4 acc = (f32x4){0.f, 0.f, 0.f, 0.f};
        #pragma unroll
        for (int s = 0; s < 4; ++s) {
            int k = wv * 128 + s * 32 + kg * 8;
            bf16x8 af = *(const bf16x8*)&fws[col * 520 + k];
            bf16x8 bg = *(const bf16x8*)&h3s[col * 520 + k];
            acc = __builtin_amdgcn_mfma_f32_16x16x32_bf16(af, bg, acc, 0, 0, 0);
        }
        #pragma unroll
        for (int r = 0; r < 4; ++r) red[wv][kg * 4 + r][col] = acc[r];
        __syncthreads();
        int j = tid >> 4, bb = tid & 15;
        float s = red[0][j][bb] + red[1][j][bb] + red[2][j][bb] + red[3][j][bb];
        fcp[((size_t)ch * 112 + j0 + j) * 16 + bb] = s;
    }
}

// out[b][j] = fb[j] + sum over live chunks of fcp[ch][j][b]
__global__ void fc_final(const float* __restrict__ fcp, const int* __restrict__ flags,
                         const float* __restrict__ fb, float* __restrict__ outp) {
    int j = blockIdx.x;
    int lane = threadIdx.x;
    float acc[16];
    #pragma unroll
    for (int b = 0; b < 16; ++b) acc[b] = 0.f;
    for (int ch = lane; ch < 768; ch += 64) {
        if (flags[ch]) {
            const float* p = &fcp[((size_t)ch * 112 + j) * 16];
            #pragma unroll
            for (int b = 0; b < 16; ++b) acc[b] += p[b];
        }
    }
    #pragma unroll
    for (int off = 32; off >= 1; off >>= 1)
        #pragma unroll
        for (int b = 0; b < 16; ++b) acc[b] += __shfl_down(acc[b], off);
    if (lane == 0) {
        float bj = fb[j];
        #pragma unroll
        for (int b = 0; b < 16; ++b) outp[b * 100 + j] = bj + acc[b];
    }
}

// ---------- launch ----------
extern "C" void kernel_launch(void* const* d_in, const int* in_sizes, int n_in,
                              void* d_out, int out_size, void* d_ws, size_t ws_size,
                              hipStream_t stream) {
    const float* x      = (const float*)d_in[0];
    const float* w1     = (const float*)d_in[1];
    const float* std1   = (const float*)d_in[2];
    const float* bias1  = (const float*)d_in[3];
    const float* alpha1 = (const float*)d_in[4];
    const float* w2     = (const float*)d_in[5];
    const float* std2   = (const float*)d_in[6];
    const float* bias2  = (const float*)d_in[7];
    const float* alpha2 = (const float*)d_in[8];
    const float* w3     = (const float*)d_in[9];
    const float* std3   = (const float*)d_in[10];
    const float* bias3  = (const float*)d_in[11];
    const float* fc_w   = (const float*)d_in[12];
    const float* fc_b   = (const float*)d_in[13];
    float* out = (float*)d_out;
    float* ws  = (float*)d_ws;

    // float region
    float* pn1   = ws;                  // 262144
    float* sbuf  = pn1 + 262144;        // 262144
    float* pn2   = sbuf + 262144;       // 65536
    float* pn3   = pn2 + 65536;         // 16384
    float* fcp   = pn3 + 16384;         // 1376256
    float* wn1   = fcp + 1376256;       // 96
    float* wn2   = wn1 + 96;            // 192
    float* wn3   = wn2 + 192;           // 384
    int*   flags = (int*)(wn3 + 384);   // 768
    float* rest  = wn3 + 384 + 768 + 32;
    // ushort region
    unsigned short* h1bf = (unsigned short*)rest;  // 6291456
    unsigned short* h2bf = h1bf + 6291456;         // 3145728
    unsigned short* h3bf = h2bf + 3145728;         // 6291456
    unsigned short* xbf  = h3bf + 6291456;         // 1048576
    unsigned short* w1r  = xbf + 1048576;          // 13056
    unsigned short* w2r  = w1r + 13056;            // 479232
    unsigned short* w3r  = w2r + 479232;           // 368640
    unsigned short* zerob = w3r + 368640;          // 64

    dim3 B(TPB);

    // ---- prep ----
    xbf_prep_sq<<<dim3(1024), B, 0, stream>>>(x, xbf, sbuf);
    wt_all<<<dim3(3364), B, 0, stream>>>(w1, w2, w3, w1r, w2r, w3r, zerob);
    wn_all<<<dim3(672), dim3(64), 0, stream>>>(w1, w2, w3, wn1, wn2, wn3);

    // ---- block 1 ----
    win_sum_kernel<5, 2><<<dim3(1024), B, 0, stream>>>(sbuf, pn1, 128, 128);
    conv1_mfma<<<dim3(1024), B, 0, stream>>>(xbf, w1r, pn1, wn1, std1, bias1, alpha1,
                                             h1bf, sbuf);

    // ---- block 2 ----
    win_sum_kernel<5, 2><<<dim3(256), B, 0, stream>>>(sbuf, pn2, 64, 64);
    conv2_mfma<<<dim3(1024), dim3(128), 0, stream>>>(
        h1bf, w2r, pn2, wn2, std2, bias2, alpha2, zerob, h2bf);

    // ---- block 3 ----
    sq_win3<<<dim3(16), B, 0, stream>>>(h2bf, pn3);
    conv3_mfma<<<dim3(1024), dim3(128), 0, stream>>>(
        h2bf, w3r, pn3, wn3, std3, bias3, zerob, h3bf);

    // ---- fc ----
    fc_mfma<<<dim3(768), B, 0, stream>>>(h3bf, fc_w, fcp, flags);
    fc_final<<<dim3(100), dim3(64), 0, stream>>>(fcp, flags, fc_b, out);
}